// Round 1
// baseline (3754.465 us; speedup 1.0000x reference)
//
#include <hip/hip_runtime.h>
#include <hip/hip_bf16.h>

#define N_NODES 100000
#define N_EDGES 600000
#define DIN 64
#define DE 8
#define D 128
#define TWO_D 256
#define L_LAYERS 5
#define BN_EPS 1e-5f

// ---------------- CSR build ----------------

__global__ void hist_kernel(const int* __restrict__ dst, int* __restrict__ deg) {
    int i = blockIdx.x * blockDim.x + threadIdx.x;
    if (i < N_EDGES) atomicAdd(&deg[dst[i]], 1);
}

__global__ void scan_kernel(const int* __restrict__ deg, int* __restrict__ rowptr,
                            int* __restrict__ cursor) {
    __shared__ int part[1024];
    const int CH = (N_NODES + 1023) / 1024;  // 98
    int t = threadIdx.x;
    int s = t * CH;
    int e = s + CH; if (e > N_NODES) e = N_NODES;
    int sum = 0;
    for (int i = s; i < e && i < N_NODES; i++) sum += deg[i];
    part[t] = sum;
    __syncthreads();
    for (int off = 1; off < 1024; off <<= 1) {
        int v = (t >= off) ? part[t - off] : 0;
        __syncthreads();
        part[t] += v;
        __syncthreads();
    }
    int run = part[t] - sum;  // exclusive prefix
    for (int i = s; i < e && i < N_NODES; i++) {
        rowptr[i] = run;
        cursor[i] = run;
        run += deg[i];
    }
    if (t == 1023) rowptr[N_NODES] = part[1023];
}

__global__ void scatter_kernel(const int* __restrict__ dst, int* __restrict__ cursor,
                               int* __restrict__ csr) {
    int i = blockIdx.x * blockDim.x + threadIdx.x;
    if (i < N_EDGES) {
        int d = dst[i];
        int p = atomicAdd(&cursor[d], 1);
        csr[p] = i;
    }
}

// ---------------- node encoder: h = x @ Wn + bn0 ----------------

__global__ void encoder_kernel(const float* __restrict__ x, const float* __restrict__ Wn,
                               const float* __restrict__ bn0, float* __restrict__ h) {
    __shared__ float WnL[DIN * D];
    __shared__ float bnL[D];
    int tid = threadIdx.x;
    for (int idx = tid; idx < DIN * D; idx += 256) WnL[idx] = Wn[idx];
    if (tid < D) bnL[tid] = bn0[tid];
    __syncthreads();
    int j = tid & 127, nsub = tid >> 7;
    for (int i = blockIdx.x * 2 + nsub; i < N_NODES; i += gridDim.x * 2) {
        const float* xr = x + (size_t)i * DIN;
        float acc = bnL[j];
#pragma unroll
        for (int k = 0; k < DIN; k++) acc = fmaf(xr[k], WnL[k * D + j], acc);
        h[(size_t)i * D + j] = acc;
    }
}

// ---------------- per-layer gather: agg[n] = sum_{e: dst=n} relu(h[src]+ea@We+bee) ----

__global__ void gather_kernel(const float* __restrict__ h, const float* __restrict__ ea,
                              const int* __restrict__ src, const int* __restrict__ rowptr,
                              const int* __restrict__ csr, const float* __restrict__ We,
                              const float* __restrict__ bee, float* __restrict__ agg) {
    __shared__ float WeL[DE * D];
    __shared__ float beeL[D];
    int tid = threadIdx.x;
    for (int idx = tid; idx < DE * D; idx += 256) WeL[idx] = We[idx];
    if (tid < D) beeL[tid] = bee[tid];
    __syncthreads();
    int j = tid & 127, nsub = tid >> 7;
    for (int n = blockIdx.x * 2 + nsub; n < N_NODES; n += gridDim.x * 2) {
        int s0 = rowptr[n], s1 = rowptr[n + 1];
        float acc = 0.f;
        for (int idx = s0; idx < s1; idx++) {
            int e = csr[idx];
            int s = src[e];
            const float* eav = ea + (size_t)e * DE;
            float eev = beeL[j];
#pragma unroll
            for (int k = 0; k < DE; k++) eev = fmaf(eav[k], WeL[k * D + j], eev);
            acc += fmaxf(h[(size_t)s * D + j] + eev, 0.f);
        }
        agg[(size_t)n * D + j] = acc;
    }
}

// ---------------- GEMM1: t = ((1+eps)*h + agg) @ W1 + b1, accumulate BN stats ----

__launch_bounds__(256, 2)
__global__ void gemm1_kernel(const float* __restrict__ h, const float* __restrict__ agg,
                             const float* __restrict__ W1, const float* __restrict__ b1,
                             const float* __restrict__ epsArr, int layer,
                             float* __restrict__ tout, float* __restrict__ colsum,
                             float* __restrict__ colsumsq) {
    __shared__ float zs[128 * 68];
    __shared__ float wsh[128 * 68];
    int tid = threadIdx.x;
    int row0 = blockIdx.x * 64;
    int cb = blockIdx.y;  // 0..3 (64-col tiles of 256)
    float epsv = 1.0f + epsArr[layer];
    {   // z tile load (k-major, transposed: zs[k][i])
        int k = tid & 127, ig = tid >> 7;
#pragma unroll
        for (int it = 0; it < 8; it++) {
            int i0 = it * 8 + ig * 4;
            float tmp[4];
#pragma unroll
            for (int r = 0; r < 4; r++) {
                int row = row0 + i0 + r;
                tmp[r] = (row < N_NODES)
                             ? fmaf(epsv, h[(size_t)row * D + k], agg[(size_t)row * D + k])
                             : 0.f;
            }
            *(float4*)&zs[k * 68 + i0] = make_float4(tmp[0], tmp[1], tmp[2], tmp[3]);
        }
    }
    {   // W tile load: wsh[k][j]
        int j4 = tid & 15, kq = tid >> 4;
#pragma unroll
        for (int m = 0; m < 8; m++) {
            int kk = kq + m * 16;
            float4 w = *(const float4*)&W1[(size_t)kk * TWO_D + cb * 64 + j4 * 4];
            *(float4*)&wsh[kk * 68 + j4 * 4] = w;
        }
    }
    __syncthreads();
    int tx = tid & 15, ty = tid >> 4;
    float acc[4][4] = {};
#pragma unroll 8
    for (int k = 0; k < 128; k++) {
        float za[4], wb[4];
        *(float4*)za = *(const float4*)&zs[k * 68 + ty * 4];
        *(float4*)wb = *(const float4*)&wsh[k * 68 + tx * 4];
#pragma unroll
        for (int r = 0; r < 4; r++)
#pragma unroll
            for (int c = 0; c < 4; c++) acc[r][c] = fmaf(za[r], wb[c], acc[r][c]);
    }
    // epilogue: add bias, store, local BN stats
    float s1[4] = {0, 0, 0, 0}, s2[4] = {0, 0, 0, 0};
    float bias[4];
    *(float4*)bias = *(const float4*)&b1[cb * 64 + tx * 4];
#pragma unroll
    for (int r = 0; r < 4; r++) {
        int row = row0 + ty * 4 + r;
        if (row < N_NODES) {
            float o[4];
#pragma unroll
            for (int c = 0; c < 4; c++) {
                o[c] = acc[r][c] + bias[c];
                s1[c] += o[c];
                s2[c] += o[c] * o[c];
            }
            *(float4*)&tout[(size_t)row * TWO_D + cb * 64 + tx * 4] = *(float4*)o;
        }
    }
    __syncthreads();  // zs reuse as reduction scratch
    float* red1 = zs;
    float* red2 = zs + 64 * 17;
#pragma unroll
    for (int c = 0; c < 4; c++) {
        red1[(tx * 4 + c) * 17 + ty] = s1[c];
        red2[(tx * 4 + c) * 17 + ty] = s2[c];
    }
    __syncthreads();
    if (tid < 64) {
        float a = 0, b = 0;
#pragma unroll
        for (int q = 0; q < 16; q++) {
            a += red1[tid * 17 + q];
            b += red2[tid * 17 + q];
        }
        atomicAdd(&colsum[cb * 64 + tid], a);
        atomicAdd(&colsumsq[cb * 64 + tid], b);
    }
}

// ---------------- GEMM2: u = relu(a1*t+b1f) @ W2 + b2, accumulate BN stats ----

__launch_bounds__(256, 2)
__global__ void gemm2_kernel(const float* __restrict__ tin, const float* __restrict__ aff_a,
                             const float* __restrict__ aff_b, const float* __restrict__ W2,
                             const float* __restrict__ b2, float* __restrict__ u,
                             float* __restrict__ colsum, float* __restrict__ colsumsq) {
    __shared__ float zs[128 * 68];
    __shared__ float wsh[128 * 68];
    int tid = threadIdx.x;
    int row0 = blockIdx.x * 64;
    int cb = blockIdx.y;  // 0..1 (64-col tiles of 128)
    int tx = tid & 15, ty = tid >> 4;
    float acc[4][4] = {};
    for (int kc = 0; kc < 2; kc++) {
        if (kc) __syncthreads();
        {   // z2 tile: relu(a*t+b)
            int k = tid & 127, ig = tid >> 7;
            int kk = kc * 128 + k;
            float a_ = aff_a[kk], b_ = aff_b[kk];
#pragma unroll
            for (int it = 0; it < 8; it++) {
                int i0 = it * 8 + ig * 4;
                float tmp[4];
#pragma unroll
                for (int r = 0; r < 4; r++) {
                    int row = row0 + i0 + r;
                    tmp[r] = (row < N_NODES)
                                 ? fmaxf(fmaf(a_, tin[(size_t)row * TWO_D + kk], b_), 0.f)
                                 : 0.f;
                }
                *(float4*)&zs[k * 68 + i0] = make_float4(tmp[0], tmp[1], tmp[2], tmp[3]);
            }
            int j4 = tid & 15, kq = tid >> 4;
#pragma unroll
            for (int m = 0; m < 8; m++) {
                int k2 = kq + m * 16;
                float4 w = *(const float4*)&W2[(size_t)(kc * 128 + k2) * D + cb * 64 + j4 * 4];
                *(float4*)&wsh[k2 * 68 + j4 * 4] = w;
            }
        }
        __syncthreads();
#pragma unroll 8
        for (int k = 0; k < 128; k++) {
            float za[4], wb[4];
            *(float4*)za = *(const float4*)&zs[k * 68 + ty * 4];
            *(float4*)wb = *(const float4*)&wsh[k * 68 + tx * 4];
#pragma unroll
            for (int r = 0; r < 4; r++)
#pragma unroll
                for (int c = 0; c < 4; c++) acc[r][c] = fmaf(za[r], wb[c], acc[r][c]);
        }
    }
    float s1[4] = {0, 0, 0, 0}, s2[4] = {0, 0, 0, 0};
    float bias[4];
    *(float4*)bias = *(const float4*)&b2[cb * 64 + tx * 4];
#pragma unroll
    for (int r = 0; r < 4; r++) {
        int row = row0 + ty * 4 + r;
        if (row < N_NODES) {
            float o[4];
#pragma unroll
            for (int c = 0; c < 4; c++) {
                o[c] = acc[r][c] + bias[c];
                s1[c] += o[c];
                s2[c] += o[c] * o[c];
            }
            *(float4*)&u[(size_t)row * D + cb * 64 + tx * 4] = *(float4*)o;
        }
    }
    __syncthreads();
    float* red1 = zs;
    float* red2 = zs + 64 * 17;
#pragma unroll
    for (int c = 0; c < 4; c++) {
        red1[(tx * 4 + c) * 17 + ty] = s1[c];
        red2[(tx * 4 + c) * 17 + ty] = s2[c];
    }
    __syncthreads();
    if (tid < 64) {
        float a = 0, b = 0;
#pragma unroll
        for (int q = 0; q < 16; q++) {
            a += red1[tid * 17 + q];
            b += red2[tid * 17 + q];
        }
        atomicAdd(&colsum[cb * 64 + tid], a);
        atomicAdd(&colsumsq[cb * 64 + tid], b);
    }
}

// ---------------- BN finalize: fold batch stats + gamma/beta into affine ----

__global__ void finalize_kernel(const float* __restrict__ colsum, const float* __restrict__ colsumsq,
                                const float* __restrict__ g, const float* __restrict__ bt,
                                float* __restrict__ aff_a, float* __restrict__ aff_b, int ncols) {
    int j = threadIdx.x;
    if (j < ncols) {
        const float invN = 1.0f / (float)N_NODES;
        float mean = colsum[j] * invN;
        float var = colsumsq[j] * invN - mean * mean;
        float rstd = rsqrtf(var + BN_EPS);
        float a = g[j] * rstd;
        aff_a[j] = a;
        aff_b[j] = fmaf(-a, mean, bt[j]);
    }
}

// ---------------- BN2 apply (+ optional relu) -> h ----------------

__global__ void apply_kernel(const float* __restrict__ u, const float* __restrict__ a,
                             const float* __restrict__ b, float* __restrict__ h, int do_relu) {
    const int total = N_NODES * D / 4;
    for (int idx = blockIdx.x * blockDim.x + threadIdx.x; idx < total;
         idx += gridDim.x * blockDim.x) {
        int j4 = idx & 31;  // 32 float4 per row
        float4 uv = ((const float4*)u)[idx];
        float4 av = ((const float4*)a)[j4];
        float4 bv = ((const float4*)b)[j4];
        float4 o;
        o.x = fmaf(av.x, uv.x, bv.x);
        o.y = fmaf(av.y, uv.y, bv.y);
        o.z = fmaf(av.z, uv.z, bv.z);
        o.w = fmaf(av.w, uv.w, bv.w);
        if (do_relu) {
            o.x = fmaxf(o.x, 0.f); o.y = fmaxf(o.y, 0.f);
            o.z = fmaxf(o.z, 0.f); o.w = fmaxf(o.w, 0.f);
        }
        ((float4*)h)[idx] = o;
    }
}

// ---------------- launch ----------------

extern "C" void kernel_launch(void* const* d_in, const int* in_sizes, int n_in,
                              void* d_out, int out_size, void* d_ws, size_t ws_size,
                              hipStream_t stream) {
    (void)in_sizes; (void)n_in; (void)out_size; (void)ws_size;
    const float* x    = (const float*)d_in[0];
    const int*   ei   = (const int*)d_in[1];
    const float* ea   = (const float*)d_in[2];
    const float* Wn   = (const float*)d_in[3];
    const float* bn0  = (const float*)d_in[4];
    const float* We   = (const float*)d_in[5];
    const float* bee  = (const float*)d_in[6];
    const float* W1   = (const float*)d_in[7];
    const float* b1   = (const float*)d_in[8];
    const float* g1   = (const float*)d_in[9];
    const float* bt1  = (const float*)d_in[10];
    const float* W2   = (const float*)d_in[11];
    const float* b2   = (const float*)d_in[12];
    const float* eps  = (const float*)d_in[13];
    const float* gamma= (const float*)d_in[14];
    const float* beta = (const float*)d_in[15];
    float* h = (float*)d_out;

    float* agg    = (float*)d_ws;                       // N*D (also reused as u)
    float* tbuf   = agg + (size_t)N_NODES * D;          // N*256
    int*   rowptr = (int*)(tbuf + (size_t)N_NODES * TWO_D);
    int*   cursor = rowptr + (N_NODES + 1);
    int*   deg    = cursor + N_NODES;
    int*   csr    = deg + N_NODES;
    float* stats  = (float*)(csr + N_EDGES);
    // stats layout: [0:256) colsum1 | [256:512) sumsq1 | [512:640) colsum2 |
    //               [640:768) sumsq2 | [768:1024) aff1a | [1024:1280) aff1b |
    //               [1280:1408) aff2a | [1408:1536) aff2b

    const int* srcA = ei;
    const int* dstA = ei + N_EDGES;

    // CSR build (once per call)
    hipMemsetAsync(deg, 0, N_NODES * sizeof(int), stream);
    hist_kernel<<<(N_EDGES + 255) / 256, 256, 0, stream>>>(dstA, deg);
    scan_kernel<<<1, 1024, 0, stream>>>(deg, rowptr, cursor);
    scatter_kernel<<<(N_EDGES + 255) / 256, 256, 0, stream>>>(dstA, cursor, csr);

    encoder_kernel<<<1024, 256, 0, stream>>>(x, Wn, bn0, h);

    for (int l = 0; l < L_LAYERS; l++) {
        gather_kernel<<<2048, 256, 0, stream>>>(h, ea, srcA, rowptr, csr,
                                                We + (size_t)l * DE * D, bee + (size_t)l * D, agg);
        hipMemsetAsync(stats, 0, 768 * sizeof(float), stream);
        gemm1_kernel<<<dim3(1563, 4), 256, 0, stream>>>(
            h, agg, W1 + (size_t)l * D * TWO_D, b1 + (size_t)l * TWO_D, eps, l, tbuf,
            stats, stats + 256);
        finalize_kernel<<<1, 256, 0, stream>>>(stats, stats + 256, g1 + (size_t)l * TWO_D,
                                               bt1 + (size_t)l * TWO_D, stats + 768,
                                               stats + 1024, TWO_D);
        gemm2_kernel<<<dim3(1563, 2), 256, 0, stream>>>(
            tbuf, stats + 768, stats + 1024, W2 + (size_t)l * TWO_D * D,
            b2 + (size_t)l * D, agg, stats + 512, stats + 640);
        finalize_kernel<<<1, 256, 0, stream>>>(stats + 512, stats + 640, gamma + (size_t)l * D,
                                               beta + (size_t)l * D, stats + 1280,
                                               stats + 1408, D);
        apply_kernel<<<4096, 256, 0, stream>>>(agg, stats + 1280, stats + 1408, h,
                                               (l < L_LAYERS - 1) ? 1 : 0);
    }
}

// Round 3
// 3290.540 us; speedup vs baseline: 1.1410x; 1.1410x over previous
//
#include <hip/hip_runtime.h>
#include <hip/hip_bf16.h>

#define N_NODES 100000
#define N_EDGES 600000
#define DIN 64
#define DE 8
#define D 128
#define TWO_D 256
#define L_LAYERS 5
#define BN_EPS 1e-5f

typedef unsigned short u16;
typedef __attribute__((ext_vector_type(8))) short short8;   // 8 bf16 MFMA A/B frag
typedef __attribute__((ext_vector_type(4))) float f32x4;    // MFMA C/D frag

__device__ inline u16 f2bf(float f) {
    __hip_bfloat16 h = __float2bfloat16(f);
    return *reinterpret_cast<u16*>(&h);
}
__device__ inline float bf2f(u16 u) {
    union { unsigned int i; float f; } v;
    v.i = ((unsigned int)u) << 16;
    return v.f;
}

// ---------------- CSR build ----------------

__global__ void hist_kernel(const int* __restrict__ dst, int* __restrict__ deg) {
    int i = blockIdx.x * blockDim.x + threadIdx.x;
    if (i < N_EDGES) atomicAdd(&deg[dst[i]], 1);
}

// in-place: cur[] holds degrees on entry, running-prefix (cursor) on exit
__global__ void scan_kernel(int* __restrict__ cur, int* __restrict__ rowptr) {
    __shared__ int part[1024];
    const int CH = (N_NODES + 1023) / 1024;
    int t = threadIdx.x;
    int s = t * CH;
    int e = s + CH; if (e > N_NODES) e = N_NODES;
    int sum = 0;
    for (int i = s; i < e; i++) sum += cur[i];
    part[t] = sum;
    __syncthreads();
    for (int off = 1; off < 1024; off <<= 1) {
        int v = (t >= off) ? part[t - off] : 0;
        __syncthreads();
        part[t] += v;
        __syncthreads();
    }
    int run = part[t] - sum;  // exclusive prefix
    for (int i = s; i < e; i++) {
        int d = cur[i];
        rowptr[i] = run;
        cur[i] = run;
        run += d;
    }
    if (t == 1023) rowptr[N_NODES] = part[1023];
}

__global__ void scatter_kernel(const int* __restrict__ dst, int* __restrict__ cursor,
                               int* __restrict__ csr) {
    int i = blockIdx.x * blockDim.x + threadIdx.x;
    if (i < N_EDGES) {
        int d = dst[i];
        int p = atomicAdd(&cursor[d], 1);
        csr[p] = i;
    }
}

// ---------------- node encoder: u = x @ Wn + bn0 (fp32) ----------------

__global__ void encoder_kernel(const float* __restrict__ x, const float* __restrict__ Wn,
                               const float* __restrict__ bn0, float* __restrict__ u) {
    __shared__ float WnL[DIN * D];
    __shared__ float bnL[D];
    int tid = threadIdx.x;
    for (int idx = tid; idx < DIN * D; idx += 256) WnL[idx] = Wn[idx];
    if (tid < D) bnL[tid] = bn0[tid];
    __syncthreads();
    int j = tid & 127, half = tid >> 7;
    for (int i = blockIdx.x * 2 + half; i < N_NODES; i += gridDim.x * 2) {
        const float* xr = x + (size_t)i * DIN;
        float acc = bnL[j];
#pragma unroll
        for (int k = 0; k < DIN; k++) acc = fmaf(xr[k], WnL[k * D + j], acc);
        u[(size_t)i * D + j] = acc;
    }
}

// ---------------- front: fused [BN2-apply ∘ gather ∘ GEMM1] ----------------
// h[n] = use_aff ? relu(aff2(u[n])) : u[n]        (fp32, on the fly)
// z[n] = (1+eps)*h[n] + sum_{e:dst=n} relu(h[src]+ea@We+bee)   (fp32)
// t = z @ W1 + b1 (split-bf16 MFMA, fp32 acc) ; BN1 stats on fp32 t

__launch_bounds__(512, 2)
__global__ void front_kernel(const float* __restrict__ u, const float* __restrict__ ea,
                             const int* __restrict__ src, const int* __restrict__ rowptr,
                             const int* __restrict__ csr, const float* __restrict__ We,
                             const float* __restrict__ bee, const float* __restrict__ epsArr,
                             int layer, int use_aff, const float* __restrict__ aff2a,
                             const float* __restrict__ aff2b, const float* __restrict__ W1,
                             const float* __restrict__ b1, float* __restrict__ t,
                             float* __restrict__ s1, float* __restrict__ s1sq) {
    __shared__ u16 Ah[128 * 136];
    __shared__ u16 Al[128 * 136];
    __shared__ u16 Bs[256 * 136];
    __shared__ float WeL[DE * D];
    __shared__ float beeL[D];
    __shared__ float affA[D];
    __shared__ float affB[D];
    __shared__ float sred[512];

    int tid = threadIdx.x;
    int row0 = blockIdx.x * 128;

    for (int i = tid; i < DE * D; i += 512) WeL[i] = We[i];
    if (tid < D) {
        beeL[tid] = bee[tid];
        affA[tid] = aff2a[tid];
        affB[tid] = aff2b[tid];
    }
    sred[tid] = 0.f;
    __syncthreads();

    // ---- B staging: W1 fp32 [128][256] -> Bs[n][k] bf16, transposed ----
    {
        // 32768 elems = 8192 float4; 16 per thread
#pragma unroll
        for (int p = 0; p < 16; p++) {
            int idx = tid + p * 512;
            int k = idx >> 6, n4 = (idx & 63) * 4;
            float4 w = *(const float4*)(W1 + (size_t)k * TWO_D + n4);
            Bs[(n4 + 0) * 136 + k] = f2bf(w.x);
            Bs[(n4 + 1) * 136 + k] = f2bf(w.y);
            Bs[(n4 + 2) * 136 + k] = f2bf(w.z);
            Bs[(n4 + 3) * 136 + k] = f2bf(w.w);
        }
    }

    // ---- gather phase: 8 rows in flight, thread handles features j and j+64 ----
    float epsv = 1.0f + epsArr[layer];
    int j = tid & 63, sub = tid >> 6;
    for (int r = sub; r < 128; r += 8) {
        int n = row0 + r;
        float za = 0.f, zb = 0.f;
        if (n < N_NODES) {
            int p0 = rowptr[n], p1 = rowptr[n + 1];
            float acc_a = 0.f, acc_b = 0.f;
            int eN = 0, sN = 0;
            float4 eaN0 = make_float4(0, 0, 0, 0), eaN1 = make_float4(0, 0, 0, 0);
            float vNa = 0.f, vNb = 0.f;
            if (p0 < p1) {
                eN = csr[p0];
                sN = src[eN];
                eaN0 = *(const float4*)(ea + (size_t)eN * DE);
                eaN1 = *(const float4*)(ea + (size_t)eN * DE + 4);
                vNa = u[(size_t)sN * D + j];
                vNb = u[(size_t)sN * D + 64 + j];
            }
            for (int idx = p0; idx < p1; idx++) {
                float4 e0 = eaN0, e1 = eaN1;
                float va = vNa, vb = vNb;
                if (idx + 1 < p1) {
                    eN = csr[idx + 1];
                    sN = src[eN];
                    eaN0 = *(const float4*)(ea + (size_t)eN * DE);
                    eaN1 = *(const float4*)(ea + (size_t)eN * DE + 4);
                    vNa = u[(size_t)sN * D + j];
                    vNb = u[(size_t)sN * D + 64 + j];
                }
                float ha = va, hb = vb;
                if (use_aff) {
                    ha = fmaxf(fmaf(affA[j], va, affB[j]), 0.f);
                    hb = fmaxf(fmaf(affA[64 + j], vb, affB[64 + j]), 0.f);
                }
                float eeA = beeL[j], eeB = beeL[64 + j];
                eeA = fmaf(e0.x, WeL[0 * D + j], eeA);
                eeB = fmaf(e0.x, WeL[0 * D + 64 + j], eeB);
                eeA = fmaf(e0.y, WeL[1 * D + j], eeA);
                eeB = fmaf(e0.y, WeL[1 * D + 64 + j], eeB);
                eeA = fmaf(e0.z, WeL[2 * D + j], eeA);
                eeB = fmaf(e0.z, WeL[2 * D + 64 + j], eeB);
                eeA = fmaf(e0.w, WeL[3 * D + j], eeA);
                eeB = fmaf(e0.w, WeL[3 * D + 64 + j], eeB);
                eeA = fmaf(e1.x, WeL[4 * D + j], eeA);
                eeB = fmaf(e1.x, WeL[4 * D + 64 + j], eeB);
                eeA = fmaf(e1.y, WeL[5 * D + j], eeA);
                eeB = fmaf(e1.y, WeL[5 * D + 64 + j], eeB);
                eeA = fmaf(e1.z, WeL[6 * D + j], eeA);
                eeB = fmaf(e1.z, WeL[6 * D + 64 + j], eeB);
                eeA = fmaf(e1.w, WeL[7 * D + j], eeA);
                eeB = fmaf(e1.w, WeL[7 * D + 64 + j], eeB);
                acc_a += fmaxf(ha + eeA, 0.f);
                acc_b += fmaxf(hb + eeB, 0.f);
            }
            // own-node term
            float oa = u[(size_t)n * D + j], ob = u[(size_t)n * D + 64 + j];
            if (use_aff) {
                oa = fmaxf(fmaf(affA[j], oa, affB[j]), 0.f);
                ob = fmaxf(fmaf(affA[64 + j], ob, affB[64 + j]), 0.f);
            }
            za = fmaf(epsv, oa, acc_a);
            zb = fmaf(epsv, ob, acc_b);
        }
        u16 hi_a = f2bf(za);
        u16 hi_b = f2bf(zb);
        Ah[r * 136 + j] = hi_a;
        Ah[r * 136 + 64 + j] = hi_b;
        Al[r * 136 + j] = f2bf(za - bf2f(hi_a));
        Al[r * 136 + 64 + j] = f2bf(zb - bf2f(hi_b));
    }
    __syncthreads();

    // ---- MFMA: 8 waves, 2x4 grid of 64x64 wave tiles (128 rows x 256 cols) ----
    int lane = tid & 63, wave = tid >> 6;
    int wr = wave >> 2, wc = wave & 3;
    int m16 = lane & 15, kq = lane >> 4;
    f32x4 acc[4][4];
#pragma unroll
    for (int i = 0; i < 4; i++)
#pragma unroll
        for (int c = 0; c < 4; c++) acc[i][c] = (f32x4){0.f, 0.f, 0.f, 0.f};
#pragma unroll
    for (int ks = 0; ks < 4; ks++) {
        int k0 = ks * 32 + kq * 8;
        short8 ah[4], al[4], bfr[4];
#pragma unroll
        for (int rt = 0; rt < 4; rt++) {
            ah[rt] = *(const short8*)(&Ah[(wr * 64 + rt * 16 + m16) * 136 + k0]);
            al[rt] = *(const short8*)(&Al[(wr * 64 + rt * 16 + m16) * 136 + k0]);
        }
#pragma unroll
        for (int ct = 0; ct < 4; ct++)
            bfr[ct] = *(const short8*)(&Bs[(wc * 64 + ct * 16 + m16) * 136 + k0]);
#pragma unroll
        for (int rt = 0; rt < 4; rt++)
#pragma unroll
            for (int ct = 0; ct < 4; ct++) {
                acc[rt][ct] = __builtin_amdgcn_mfma_f32_16x16x32_bf16(ah[rt], bfr[ct],
                                                                     acc[rt][ct], 0, 0, 0);
                acc[rt][ct] = __builtin_amdgcn_mfma_f32_16x16x32_bf16(al[rt], bfr[ct],
                                                                     acc[rt][ct], 0, 0, 0);
            }
    }

    // ---- epilogue: bias, direct fp32 store to t, BN1 stats ----
#pragma unroll
    for (int ct = 0; ct < 4; ct++) {
        int col = wc * 64 + ct * 16 + m16;
        float bias = b1[col];
        float ls = 0.f, lq = 0.f;
#pragma unroll
        for (int rt = 0; rt < 4; rt++) {
#pragma unroll
            for (int rr = 0; rr < 4; rr++) {
                int row = row0 + wr * 64 + rt * 16 + kq * 4 + rr;
                if (row < N_NODES) {
                    float v = acc[rt][ct][rr] + bias;
                    t[(size_t)row * TWO_D + col] = v;
                    ls += v;
                    lq += v * v;
                }
            }
        }
        atomicAdd(&sred[col], ls);
        atomicAdd(&sred[256 + col], lq);
    }
    __syncthreads();
    int slot = blockIdx.x & 7;
    if (tid < 256) atomicAdd(&s1[slot * TWO_D + tid], sred[tid]);
    else atomicAdd(&s1sq[slot * TWO_D + (tid - 256)], sred[tid]);
}

// ---------------- GEMM2: u = relu(aff1(t)) @ W2 + b2 (split-bf16 MFMA), BN2 stats ----

__launch_bounds__(256, 2)
__global__ void gemm2_kernel(const float* __restrict__ t, const float* __restrict__ aff1a,
                             const float* __restrict__ aff1b, const float* __restrict__ W2,
                             const float* __restrict__ b2, float* __restrict__ u,
                             float* __restrict__ s2, float* __restrict__ s2sq) {
    __shared__ u16 Ah[128 * 72];
    __shared__ u16 Al[128 * 72];
    __shared__ u16 Bs[128 * 72];
    __shared__ float affL[512];
    __shared__ float sred[256];

    int tid = threadIdx.x;
    int row0 = blockIdx.x * 128;
    affL[tid] = aff1a[tid];
    affL[256 + tid] = aff1b[tid];
    sred[tid] = 0.f;
    __syncthreads();

    int lane = tid & 63, wave = tid >> 6;
    int wr = wave >> 1, wc = wave & 1;
    int m16 = lane & 15, kq = lane >> 4;
    f32x4 acc[4][4];
#pragma unroll
    for (int i = 0; i < 4; i++)
#pragma unroll
        for (int c = 0; c < 4; c++) acc[i][c] = (f32x4){0.f, 0.f, 0.f, 0.f};

    for (int kc = 0; kc < 4; kc++) {
        if (kc) __syncthreads();
        // A staging: t fp32 -> relu(aff1) -> hi/lo bf16
#pragma unroll
        for (int p = 0; p < 8; p++) {
            int idx = tid + p * 256;
            int row = idx >> 4, c4 = (idx & 15) * 4;
            float4 v = make_float4(0, 0, 0, 0);
            if (row0 + row < N_NODES)
                v = *(const float4*)(t + (size_t)(row0 + row) * TWO_D + kc * 64 + c4);
            float f[4] = {v.x, v.y, v.z, v.w};
            u16 hi4[4], lo4[4];
#pragma unroll
            for (int i = 0; i < 4; i++) {
                int k = kc * 64 + c4 + i;
                float g = fmaxf(fmaf(affL[k], f[i], affL[256 + k]), 0.f);
                u16 hi = f2bf(g);
                hi4[i] = hi;
                lo4[i] = f2bf(g - bf2f(hi));
            }
            *(uint2*)(&Ah[row * 72 + c4]) = *(const uint2*)hi4;
            *(uint2*)(&Al[row * 72 + c4]) = *(const uint2*)lo4;
        }
        // B staging: W2 fp32 [256][128] chunk -> Bs[n][k] bf16 transposed
#pragma unroll
        for (int p = 0; p < 8; p++) {
            int idx = tid + p * 256;
            int kk = idx >> 5, n4 = (idx & 31) * 4;
            float4 w = *(const float4*)(W2 + (size_t)(kc * 64 + kk) * D + n4);
            Bs[(n4 + 0) * 72 + kk] = f2bf(w.x);
            Bs[(n4 + 1) * 72 + kk] = f2bf(w.y);
            Bs[(n4 + 2) * 72 + kk] = f2bf(w.z);
            Bs[(n4 + 3) * 72 + kk] = f2bf(w.w);
        }
        __syncthreads();
#pragma unroll
        for (int ks = 0; ks < 2; ks++) {
            int k0 = ks * 32 + kq * 8;
            short8 ah[4], al[4], bfr[4];
#pragma unroll
            for (int rt = 0; rt < 4; rt++) {
                ah[rt] = *(const short8*)(&Ah[(wr * 64 + rt * 16 + m16) * 72 + k0]);
                al[rt] = *(const short8*)(&Al[(wr * 64 + rt * 16 + m16) * 72 + k0]);
            }
#pragma unroll
            for (int ct = 0; ct < 4; ct++)
                bfr[ct] = *(const short8*)(&Bs[(wc * 64 + ct * 16 + m16) * 72 + k0]);
#pragma unroll
            for (int rt = 0; rt < 4; rt++)
#pragma unroll
                for (int ct = 0; ct < 4; ct++) {
                    acc[rt][ct] = __builtin_amdgcn_mfma_f32_16x16x32_bf16(ah[rt], bfr[ct],
                                                                         acc[rt][ct], 0, 0, 0);
                    acc[rt][ct] = __builtin_amdgcn_mfma_f32_16x16x32_bf16(al[rt], bfr[ct],
                                                                         acc[rt][ct], 0, 0, 0);
                }
        }
    }

    // epilogue: bias, direct fp32 store to u, BN2 stats
#pragma unroll
    for (int ct = 0; ct < 4; ct++) {
        int col = wc * 64 + ct * 16 + m16;
        float bias = b2[col];
        float ls = 0.f, lq = 0.f;
#pragma unroll
        for (int rt = 0; rt < 4; rt++) {
#pragma unroll
            for (int rr = 0; rr < 4; rr++) {
                int row = row0 + wr * 64 + rt * 16 + kq * 4 + rr;
                if (row < N_NODES) {
                    float v = acc[rt][ct][rr] + bias;
                    u[(size_t)row * D + col] = v;
                    ls += v;
                    lq += v * v;
                }
            }
        }
        atomicAdd(&sred[col], ls);
        atomicAdd(&sred[128 + col], lq);
    }
    __syncthreads();
    int slot = blockIdx.x & 7;
    if (tid < 128) atomicAdd(&s2[slot * D + tid], sred[tid]);
    else if (tid < 256) atomicAdd(&s2sq[slot * D + (tid - 128)], sred[tid]);
}

// ---------------- BN finalize ----------------

__global__ void finalize_kernel(const float* __restrict__ sums, const float* __restrict__ sumsq,
                                int ncols, const float* __restrict__ g,
                                const float* __restrict__ bt, float* __restrict__ affa,
                                float* __restrict__ affb) {
    int j = threadIdx.x;
    if (j < ncols) {
        float s = 0.f, q = 0.f;
        for (int k = 0; k < 8; k++) { s += sums[k * ncols + j]; q += sumsq[k * ncols + j]; }
        const float invN = 1.0f / (float)N_NODES;
        float mean = s * invN;
        float var = q * invN - mean * mean;
        float rstd = rsqrtf(var + BN_EPS);
        float a = g[j] * rstd;
        affa[j] = a;
        affb[j] = fmaf(-a, mean, bt[j]);
    }
}

// ---------------- final BN2 apply (no relu) -> out ----------------

__global__ void apply_final_kernel(const float* __restrict__ u, const float* __restrict__ a,
                                   const float* __restrict__ b, float* __restrict__ out) {
    const int total = N_NODES * D / 4;
    for (int idx = blockIdx.x * blockDim.x + threadIdx.x; idx < total;
         idx += gridDim.x * blockDim.x) {
        int j4 = (idx & 31) * 4;
        float4 uv = ((const float4*)u)[idx];
        float4 av = *(const float4*)(a + j4);
        float4 bv = *(const float4*)(b + j4);
        float4 o;
        o.x = fmaf(av.x, uv.x, bv.x);
        o.y = fmaf(av.y, uv.y, bv.y);
        o.z = fmaf(av.z, uv.z, bv.z);
        o.w = fmaf(av.w, uv.w, bv.w);
        ((float4*)out)[idx] = o;
    }
}

// ---------------- launch ----------------

extern "C" void kernel_launch(void* const* d_in, const int* in_sizes, int n_in,
                              void* d_out, int out_size, void* d_ws, size_t ws_size,
                              hipStream_t stream) {
    (void)in_sizes; (void)n_in; (void)out_size; (void)ws_size;
    const float* x    = (const float*)d_in[0];
    const int*   ei   = (const int*)d_in[1];
    const float* ea   = (const float*)d_in[2];
    const float* Wn   = (const float*)d_in[3];
    const float* bn0  = (const float*)d_in[4];
    const float* We   = (const float*)d_in[5];
    const float* bee  = (const float*)d_in[6];
    const float* W1   = (const float*)d_in[7];
    const float* b1   = (const float*)d_in[8];
    const float* g1   = (const float*)d_in[9];
    const float* bt1  = (const float*)d_in[10];
    const float* W2   = (const float*)d_in[11];
    const float* b2   = (const float*)d_in[12];
    const float* eps  = (const float*)d_in[13];
    const float* gamma= (const float*)d_in[14];
    const float* beta = (const float*)d_in[15];
    float* out = (float*)d_out;

    // workspace layout (total ~156.9 MB)
    float* u      = (float*)d_ws;                      // N*128 fp32
    float* t      = u + (size_t)N_NODES * D;           // N*256 fp32
    int*   rowptr = (int*)(t + (size_t)N_NODES * TWO_D);  // N+1
    int*   cursor = rowptr + (N_NODES + 1);            // N (deg then cursor, in place)
    int*   csr    = cursor + N_NODES;                  // E
    float* stats  = (float*)(csr + N_EDGES);
    float* s1    = stats;            // [8][256]
    float* s1sq  = stats + 2048;     // [8][256]
    float* s2    = stats + 4096;     // [8][128]
    float* s2sq  = stats + 5120;     // [8][128]
    float* aff1a = stats + 6144;     // [256]
    float* aff1b = stats + 6400;     // [256]
    float* aff2a = stats + 6656;     // [128]
    float* aff2b = stats + 6784;     // [128]

    const int* srcA = ei;
    const int* dstA = ei + N_EDGES;

    hipMemsetAsync(cursor, 0, N_NODES * sizeof(int), stream);
    hist_kernel<<<(N_EDGES + 255) / 256, 256, 0, stream>>>(dstA, cursor);
    scan_kernel<<<1, 1024, 0, stream>>>(cursor, rowptr);
    scatter_kernel<<<(N_EDGES + 255) / 256, 256, 0, stream>>>(dstA, cursor, csr);

    encoder_kernel<<<2048, 256, 0, stream>>>(x, Wn, bn0, u);

    const int NB = (N_NODES + 127) / 128;  // 782
    for (int l = 0; l < L_LAYERS; l++) {
        hipMemsetAsync(stats, 0, 6144 * sizeof(float), stream);
        front_kernel<<<NB, 512, 0, stream>>>(
            u, ea, srcA, rowptr, csr, We + (size_t)l * DE * D, bee + (size_t)l * D,
            eps, l, (l > 0) ? 1 : 0, aff2a, aff2b,
            W1 + (size_t)l * D * TWO_D, b1 + (size_t)l * TWO_D, t, s1, s1sq);
        finalize_kernel<<<1, 256, 0, stream>>>(s1, s1sq, TWO_D, g1 + (size_t)l * TWO_D,
                                               bt1 + (size_t)l * TWO_D, aff1a, aff1b);
        gemm2_kernel<<<NB, 256, 0, stream>>>(
            t, aff1a, aff1b, W2 + (size_t)l * TWO_D * D, b2 + (size_t)l * D, u, s2, s2sq);
        finalize_kernel<<<1, 128, 0, stream>>>(s2, s2sq, D, gamma + (size_t)l * D,
                                               beta + (size_t)l * D, aff2a, aff2b);
    }
    apply_final_kernel<<<4096, 256, 0, stream>>>(u, aff2a, aff2b, out);
}

// Round 5
// 2428.382 us; speedup vs baseline: 1.5461x; 1.3550x over previous
//
#include <hip/hip_runtime.h>
#include <hip/hip_bf16.h>

#define N_NODES 100000
#define N_EDGES 600000
#define DIN 64
#define DE 8
#define D 128
#define TWO_D 256
#define L_LAYERS 5
#define BN_EPS 1e-5f

typedef unsigned short u16;
typedef __attribute__((ext_vector_type(8))) short short8;   // 8 bf16 MFMA A/B frag
typedef __attribute__((ext_vector_type(4))) float f32x4;    // MFMA C/D frag / native float4

__device__ inline u16 f2bf(float f) {
    __hip_bfloat16 h = __float2bfloat16(f);
    return *reinterpret_cast<u16*>(&h);
}
__device__ inline float bf2f(u16 u) {
    union { unsigned int i; float f; } v;
    v.i = ((unsigned int)u) << 16;
    return v.f;
}

// ---------------- CSR build ----------------

__global__ void hist_kernel(const int* __restrict__ dst, int* __restrict__ deg) {
    int i = blockIdx.x * blockDim.x + threadIdx.x;
    if (i < N_EDGES) atomicAdd(&deg[dst[i]], 1);
}

// in-place: cur[] holds degrees on entry, running-prefix (cursor) on exit
__global__ void scan_kernel(int* __restrict__ cur, int* __restrict__ rowptr) {
    __shared__ int part[1024];
    const int CH = (N_NODES + 1023) / 1024;
    int t = threadIdx.x;
    int s = t * CH;
    int e = s + CH; if (e > N_NODES) e = N_NODES;
    int sum = 0;
    for (int i = s; i < e; i++) sum += cur[i];
    part[t] = sum;
    __syncthreads();
    for (int off = 1; off < 1024; off <<= 1) {
        int v = (t >= off) ? part[t - off] : 0;
        __syncthreads();
        part[t] += v;
        __syncthreads();
    }
    int run = part[t] - sum;  // exclusive prefix
    for (int i = s; i < e; i++) {
        int d = cur[i];
        rowptr[i] = run;
        cur[i] = run;
        run += d;
    }
    if (t == 1023) rowptr[N_NODES] = part[1023];
}

__global__ void scatter_kernel(const int* __restrict__ dst, int* __restrict__ cursor,
                               int* __restrict__ csr) {
    int i = blockIdx.x * blockDim.x + threadIdx.x;
    if (i < N_EDGES) {
        int d = dst[i];
        int p = atomicAdd(&cursor[d], 1);
        csr[p] = i;
    }
}

// ---------------- node encoder: u = x @ Wn + bn0 (fp32) ----------------

__global__ void encoder_kernel(const float* __restrict__ x, const float* __restrict__ Wn,
                               const float* __restrict__ bn0, float* __restrict__ u) {
    __shared__ float WnL[DIN * D];
    __shared__ float bnL[D];
    int tid = threadIdx.x;
    for (int idx = tid; idx < DIN * D; idx += 256) WnL[idx] = Wn[idx];
    if (tid < D) bnL[tid] = bn0[tid];
    __syncthreads();
    int j = tid & 127, half = tid >> 7;
    for (int i = blockIdx.x * 2 + half; i < N_NODES; i += gridDim.x * 2) {
        const float* xr = x + (size_t)i * DIN;
        float acc = bnL[j];
#pragma unroll
        for (int k = 0; k < DIN; k++) acc = fmaf(xr[k], WnL[k * D + j], acc);
        u[(size_t)i * D + j] = acc;
    }
}

// ---------------- front: fused [BN2-apply ∘ gather ∘ GEMM1] ----------------
// h[n] = use_aff ? relu(aff2(u[n])) : u[n]        (fp32, on the fly)
// z[n] = (1+eps)*h[n] + sum_{e:dst=n} relu(h[src]+ea@We+bee)   (fp32)
// t = z @ W1 + b1 (split-bf16 MFMA, fp32 acc) ; BN1 stats on fp32 t
// t stores are non-temporal: keep u resident in L3 for the random gather reads.

__launch_bounds__(512, 2)
__global__ void front_kernel(const float* __restrict__ u, const float* __restrict__ ea,
                             const int* __restrict__ src, const int* __restrict__ rowptr,
                             const int* __restrict__ csr, const float* __restrict__ We,
                             const float* __restrict__ bee, const float* __restrict__ epsArr,
                             int layer, int use_aff, const float* __restrict__ aff2a,
                             const float* __restrict__ aff2b, const float* __restrict__ W1,
                             const float* __restrict__ b1, float* __restrict__ t,
                             float* __restrict__ s1, float* __restrict__ s1sq) {
    __shared__ u16 Ah[128 * 136];
    __shared__ u16 Al[128 * 136];
    __shared__ u16 Bs[256 * 136];
    __shared__ float WeL[DE * D];
    __shared__ float beeL[D];
    __shared__ float affA[D];
    __shared__ float affB[D];
    __shared__ float sred[512];

    int tid = threadIdx.x;
    int row0 = blockIdx.x * 128;

    for (int i = tid; i < DE * D; i += 512) WeL[i] = We[i];
    if (tid < D) {
        beeL[tid] = bee[tid];
        affA[tid] = aff2a[tid];
        affB[tid] = aff2b[tid];
    }
    sred[tid] = 0.f;
    __syncthreads();

    // ---- B staging: W1 fp32 [128][256] -> Bs[n][k] bf16, transposed ----
    {
#pragma unroll
        for (int p = 0; p < 16; p++) {
            int idx = tid + p * 512;
            int k = idx >> 6, n4 = (idx & 63) * 4;
            float4 w = *(const float4*)(W1 + (size_t)k * TWO_D + n4);
            Bs[(n4 + 0) * 136 + k] = f2bf(w.x);
            Bs[(n4 + 1) * 136 + k] = f2bf(w.y);
            Bs[(n4 + 2) * 136 + k] = f2bf(w.z);
            Bs[(n4 + 3) * 136 + k] = f2bf(w.w);
        }
    }

    // ---- gather phase: wave handles rows r = sub+8k; 4-edge chunks, deep pipeline ----
    float epsv = 1.0f + epsArr[layer];
    int j = tid & 63, sub = tid >> 6;
    for (int r = sub; r < 128; r += 8) {
        int n = row0 + r;
        float za = 0.f, zb = 0.f;
        if (n < N_NODES) {
            int p0 = rowptr[n], p1 = rowptr[n + 1];
            int cnt = p1 - p0;
            float acc_a = 0.f, acc_b = 0.f;
            int e[4], s[4];
#pragma unroll
            for (int i = 0; i < 4; i++) e[i] = (p0 + i < p1) ? csr[p0 + i] : 0;
#pragma unroll
            for (int i = 0; i < 4; i++) s[i] = src[e[i]];
            for (int base = 0; base < cnt; base += 4) {
                int m = cnt - base;  // valid edges this chunk (wave-uniform)
                // issue all loads for current chunk (8 u-rows + 4 ea pairs, independent)
                float va[4], vb[4];
                float4 e0[4], e1[4];
#pragma unroll
                for (int i = 0; i < 4; i++) {
                    int ss = s[i];
                    va[i] = u[(size_t)ss * D + j];
                    vb[i] = u[(size_t)ss * D + 64 + j];
                    e0[i] = *(const float4*)(ea + (size_t)e[i] * DE);
                    e1[i] = *(const float4*)(ea + (size_t)e[i] * DE + 4);
                }
                // prefetch next chunk ids while u-loads are in flight
                int e2[4], s2[4];
#pragma unroll
                for (int i = 0; i < 4; i++) {
                    int p = p0 + base + 4 + i;
                    e2[i] = (p < p1) ? csr[p] : 0;
                }
#pragma unroll
                for (int i = 0; i < 4; i++) s2[i] = src[e2[i]];
                // compute current chunk
#pragma unroll
                for (int i = 0; i < 4; i++) {
                    float ha = va[i], hb = vb[i];
                    if (use_aff) {
                        ha = fmaxf(fmaf(affA[j], ha, affB[j]), 0.f);
                        hb = fmaxf(fmaf(affA[64 + j], hb, affB[64 + j]), 0.f);
                    }
                    float eeA = beeL[j], eeB = beeL[64 + j];
                    eeA = fmaf(e0[i].x, WeL[0 * D + j], eeA);
                    eeB = fmaf(e0[i].x, WeL[0 * D + 64 + j], eeB);
                    eeA = fmaf(e0[i].y, WeL[1 * D + j], eeA);
                    eeB = fmaf(e0[i].y, WeL[1 * D + 64 + j], eeB);
                    eeA = fmaf(e0[i].z, WeL[2 * D + j], eeA);
                    eeB = fmaf(e0[i].z, WeL[2 * D + 64 + j], eeB);
                    eeA = fmaf(e0[i].w, WeL[3 * D + j], eeA);
                    eeB = fmaf(e0[i].w, WeL[3 * D + 64 + j], eeB);
                    eeA = fmaf(e1[i].x, WeL[4 * D + j], eeA);
                    eeB = fmaf(e1[i].x, WeL[4 * D + 64 + j], eeB);
                    eeA = fmaf(e1[i].y, WeL[5 * D + j], eeA);
                    eeB = fmaf(e1[i].y, WeL[5 * D + 64 + j], eeB);
                    eeA = fmaf(e1[i].z, WeL[6 * D + j], eeA);
                    eeB = fmaf(e1[i].z, WeL[6 * D + 64 + j], eeB);
                    eeA = fmaf(e1[i].w, WeL[7 * D + j], eeA);
                    eeB = fmaf(e1[i].w, WeL[7 * D + 64 + j], eeB);
                    float ma = fmaxf(ha + eeA, 0.f);
                    float mb = fmaxf(hb + eeB, 0.f);
                    acc_a += (i < m) ? ma : 0.f;
                    acc_b += (i < m) ? mb : 0.f;
                }
#pragma unroll
                for (int i = 0; i < 4; i++) { e[i] = e2[i]; s[i] = s2[i]; }
            }
            // own-node term
            float oa = u[(size_t)n * D + j], ob = u[(size_t)n * D + 64 + j];
            if (use_aff) {
                oa = fmaxf(fmaf(affA[j], oa, affB[j]), 0.f);
                ob = fmaxf(fmaf(affA[64 + j], ob, affB[64 + j]), 0.f);
            }
            za = fmaf(epsv, oa, acc_a);
            zb = fmaf(epsv, ob, acc_b);
        }
        u16 hi_a = f2bf(za);
        u16 hi_b = f2bf(zb);
        Ah[r * 136 + j] = hi_a;
        Ah[r * 136 + 64 + j] = hi_b;
        Al[r * 136 + j] = f2bf(za - bf2f(hi_a));
        Al[r * 136 + 64 + j] = f2bf(zb - bf2f(hi_b));
    }
    __syncthreads();

    // ---- MFMA: 8 waves, 2x4 grid of 64x64 wave tiles (128 rows x 256 cols) ----
    int lane = tid & 63, wave = tid >> 6;
    int wr = wave >> 2, wc = wave & 3;
    int m16 = lane & 15, kq = lane >> 4;
    f32x4 acc[4][4];
#pragma unroll
    for (int i = 0; i < 4; i++)
#pragma unroll
        for (int c = 0; c < 4; c++) acc[i][c] = (f32x4){0.f, 0.f, 0.f, 0.f};
#pragma unroll
    for (int ks = 0; ks < 4; ks++) {
        int k0 = ks * 32 + kq * 8;
        short8 ah[4], al[4], bfr[4];
#pragma unroll
        for (int rt = 0; rt < 4; rt++) {
            ah[rt] = *(const short8*)(&Ah[(wr * 64 + rt * 16 + m16) * 136 + k0]);
            al[rt] = *(const short8*)(&Al[(wr * 64 + rt * 16 + m16) * 136 + k0]);
        }
#pragma unroll
        for (int ct = 0; ct < 4; ct++)
            bfr[ct] = *(const short8*)(&Bs[(wc * 64 + ct * 16 + m16) * 136 + k0]);
#pragma unroll
        for (int rt = 0; rt < 4; rt++)
#pragma unroll
            for (int ct = 0; ct < 4; ct++) {
                acc[rt][ct] = __builtin_amdgcn_mfma_f32_16x16x32_bf16(ah[rt], bfr[ct],
                                                                     acc[rt][ct], 0, 0, 0);
                acc[rt][ct] = __builtin_amdgcn_mfma_f32_16x16x32_bf16(al[rt], bfr[ct],
                                                                     acc[rt][ct], 0, 0, 0);
            }
    }

    // ---- epilogue: bias, non-temporal fp32 store to t, BN1 stats ----
#pragma unroll
    for (int ct = 0; ct < 4; ct++) {
        int col = wc * 64 + ct * 16 + m16;
        float bias = b1[col];
        float ls = 0.f, lq = 0.f;
#pragma unroll
        for (int rt = 0; rt < 4; rt++) {
#pragma unroll
            for (int rr = 0; rr < 4; rr++) {
                int row = row0 + wr * 64 + rt * 16 + kq * 4 + rr;
                if (row < N_NODES) {
                    float v = acc[rt][ct][rr] + bias;
                    __builtin_nontemporal_store(v, &t[(size_t)row * TWO_D + col]);
                    ls += v;
                    lq += v * v;
                }
            }
        }
        atomicAdd(&sred[col], ls);
        atomicAdd(&sred[256 + col], lq);
    }
    __syncthreads();
    int slot = blockIdx.x & 7;
    if (tid < 256) atomicAdd(&s1[slot * TWO_D + tid], sred[tid]);
    else atomicAdd(&s1sq[slot * TWO_D + (tid - 256)], sred[tid]);
}

// ---------------- GEMM2: u = relu(aff1(t)) @ W2 + b2 (split-bf16 MFMA), BN2 stats ----
// t loads are non-temporal (streaming, read-once).

__launch_bounds__(256, 2)
__global__ void gemm2_kernel(const float* __restrict__ t, const float* __restrict__ aff1a,
                             const float* __restrict__ aff1b, const float* __restrict__ W2,
                             const float* __restrict__ b2, float* __restrict__ u,
                             float* __restrict__ s2, float* __restrict__ s2sq) {
    __shared__ u16 Ah[128 * 72];
    __shared__ u16 Al[128 * 72];
    __shared__ u16 Bs[128 * 72];
    __shared__ float affL[512];
    __shared__ float sred[256];

    int tid = threadIdx.x;
    int row0 = blockIdx.x * 128;
    affL[tid] = aff1a[tid];
    affL[256 + tid] = aff1b[tid];
    sred[tid] = 0.f;
    __syncthreads();

    int lane = tid & 63, wave = tid >> 6;
    int wr = wave >> 1, wc = wave & 1;
    int m16 = lane & 15, kq = lane >> 4;
    f32x4 acc[4][4];
#pragma unroll
    for (int i = 0; i < 4; i++)
#pragma unroll
        for (int c = 0; c < 4; c++) acc[i][c] = (f32x4){0.f, 0.f, 0.f, 0.f};

    for (int kc = 0; kc < 4; kc++) {
        if (kc) __syncthreads();
        // A staging: t fp32 (non-temporal) -> relu(aff1) -> hi/lo bf16
#pragma unroll
        for (int p = 0; p < 8; p++) {
            int idx = tid + p * 256;
            int row = idx >> 4, c4 = (idx & 15) * 4;
            f32x4 v = (f32x4){0.f, 0.f, 0.f, 0.f};
            if (row0 + row < N_NODES)
                v = __builtin_nontemporal_load(
                        (const f32x4*)(t + (size_t)(row0 + row) * TWO_D + kc * 64 + c4));
            u16 hi4[4], lo4[4];
#pragma unroll
            for (int i = 0; i < 4; i++) {
                int k = kc * 64 + c4 + i;
                float g = fmaxf(fmaf(affL[k], v[i], affL[256 + k]), 0.f);
                u16 hi = f2bf(g);
                hi4[i] = hi;
                lo4[i] = f2bf(g - bf2f(hi));
            }
            *(uint2*)(&Ah[row * 72 + c4]) = *(const uint2*)hi4;
            *(uint2*)(&Al[row * 72 + c4]) = *(const uint2*)lo4;
        }
        // B staging: W2 fp32 [256][128] chunk -> Bs[n][k] bf16 transposed
#pragma unroll
        for (int p = 0; p < 8; p++) {
            int idx = tid + p * 256;
            int kk = idx >> 5, n4 = (idx & 31) * 4;
            float4 w = *(const float4*)(W2 + (size_t)(kc * 64 + kk) * D + n4);
            Bs[(n4 + 0) * 72 + kk] = f2bf(w.x);
            Bs[(n4 + 1) * 72 + kk] = f2bf(w.y);
            Bs[(n4 + 2) * 72 + kk] = f2bf(w.z);
            Bs[(n4 + 3) * 72 + kk] = f2bf(w.w);
        }
        __syncthreads();
#pragma unroll
        for (int ks = 0; ks < 2; ks++) {
            int k0 = ks * 32 + kq * 8;
            short8 ah[4], al[4], bfr[4];
#pragma unroll
            for (int rt = 0; rt < 4; rt++) {
                ah[rt] = *(const short8*)(&Ah[(wr * 64 + rt * 16 + m16) * 72 + k0]);
                al[rt] = *(const short8*)(&Al[(wr * 64 + rt * 16 + m16) * 72 + k0]);
            }
#pragma unroll
            for (int ct = 0; ct < 4; ct++)
                bfr[ct] = *(const short8*)(&Bs[(wc * 64 + ct * 16 + m16) * 72 + k0]);
#pragma unroll
            for (int rt = 0; rt < 4; rt++)
#pragma unroll
                for (int ct = 0; ct < 4; ct++) {
                    acc[rt][ct] = __builtin_amdgcn_mfma_f32_16x16x32_bf16(ah[rt], bfr[ct],
                                                                         acc[rt][ct], 0, 0, 0);
                    acc[rt][ct] = __builtin_amdgcn_mfma_f32_16x16x32_bf16(al[rt], bfr[ct],
                                                                         acc[rt][ct], 0, 0, 0);
                }
        }
    }

    // epilogue: bias, direct fp32 store to u (cacheable — next layer gathers it), BN2 stats
#pragma unroll
    for (int ct = 0; ct < 4; ct++) {
        int col = wc * 64 + ct * 16 + m16;
        float bias = b2[col];
        float ls = 0.f, lq = 0.f;
#pragma unroll
        for (int rt = 0; rt < 4; rt++) {
#pragma unroll
            for (int rr = 0; rr < 4; rr++) {
                int row = row0 + wr * 64 + rt * 16 + kq * 4 + rr;
                if (row < N_NODES) {
                    float v = acc[rt][ct][rr] + bias;
                    u[(size_t)row * D + col] = v;
                    ls += v;
                    lq += v * v;
                }
            }
        }
        atomicAdd(&sred[col], ls);
        atomicAdd(&sred[128 + col], lq);
    }
    __syncthreads();
    int slot = blockIdx.x & 7;
    if (tid < 128) atomicAdd(&s2[slot * D + tid], sred[tid]);
    else if (tid < 256) atomicAdd(&s2sq[slot * D + (tid - 128)], sred[tid]);
}

// ---------------- BN finalize ----------------

__global__ void finalize_kernel(const float* __restrict__ sums, const float* __restrict__ sumsq,
                                int ncols, const float* __restrict__ g,
                                const float* __restrict__ bt, float* __restrict__ affa,
                                float* __restrict__ affb) {
    int j = threadIdx.x;
    if (j < ncols) {
        float s = 0.f, q = 0.f;
        for (int k = 0; k < 8; k++) { s += sums[k * ncols + j]; q += sumsq[k * ncols + j]; }
        const float invN = 1.0f / (float)N_NODES;
        float mean = s * invN;
        float var = q * invN - mean * mean;
        float rstd = rsqrtf(var + BN_EPS);
        float a = g[j] * rstd;
        affa[j] = a;
        affb[j] = fmaf(-a, mean, bt[j]);
    }
}

// ---------------- final BN2 apply (no relu) -> out ----------------

__global__ void apply_final_kernel(const float* __restrict__ u, const float* __restrict__ a,
                                   const float* __restrict__ b, float* __restrict__ out) {
    const int total = N_NODES * D / 4;
    for (int idx = blockIdx.x * blockDim.x + threadIdx.x; idx < total;
         idx += gridDim.x * blockDim.x) {
        int j4 = (idx & 31) * 4;
        float4 uv = ((const float4*)u)[idx];
        float4 av = *(const float4*)(a + j4);
        float4 bv = *(const float4*)(b + j4);
        float4 o;
        o.x = fmaf(av.x, uv.x, bv.x);
        o.y = fmaf(av.y, uv.y, bv.y);
        o.z = fmaf(av.z, uv.z, bv.z);
        o.w = fmaf(av.w, uv.w, bv.w);
        ((float4*)out)[idx] = o;
    }
}

// ---------------- launch ----------------

extern "C" void kernel_launch(void* const* d_in, const int* in_sizes, int n_in,
                              void* d_out, int out_size, void* d_ws, size_t ws_size,
                              hipStream_t stream) {
    (void)in_sizes; (void)n_in; (void)out_size; (void)ws_size;
    const float* x    = (const float*)d_in[0];
    const int*   ei   = (const int*)d_in[1];
    const float* ea   = (const float*)d_in[2];
    const float* Wn   = (const float*)d_in[3];
    const float* bn0  = (const float*)d_in[4];
    const float* We   = (const float*)d_in[5];
    const float* bee  = (const float*)d_in[6];
    const float* W1   = (const float*)d_in[7];
    const float* b1   = (const float*)d_in[8];
    const float* g1   = (const float*)d_in[9];
    const float* bt1  = (const float*)d_in[10];
    const float* W2   = (const float*)d_in[11];
    const float* b2   = (const float*)d_in[12];
    const float* eps  = (const float*)d_in[13];
    const float* gamma= (const float*)d_in[14];
    const float* beta = (const float*)d_in[15];
    float* out = (float*)d_out;

    // workspace layout (total ~156.9 MB)
    float* u      = (float*)d_ws;                      // N*128 fp32
    float* t      = u + (size_t)N_NODES * D;           // N*256 fp32
    int*   rowptr = (int*)(t + (size_t)N_NODES * TWO_D);  // N+1
    int*   cursor = rowptr + (N_NODES + 1);            // N (deg then cursor, in place)
    int*   csr    = cursor + N_NODES;                  // E
    float* stats  = (float*)(csr + N_EDGES);
    float* s1    = stats;            // [8][256]
    float* s1sq  = stats + 2048;     // [8][256]
    float* s2    = stats + 4096;     // [8][128]
    float* s2sq  = stats + 5120;     // [8][128]
    float* aff1a = stats + 6144;     // [256]
    float* aff1b = stats + 6400;     // [256]
    float* aff2a = stats + 6656;     // [128]
    float* aff2b = stats + 6784;     // [128]

    const int* srcA = ei;
    const int* dstA = ei + N_EDGES;

    (void)hipMemsetAsync(cursor, 0, N_NODES * sizeof(int), stream);
    hist_kernel<<<(N_EDGES + 255) / 256, 256, 0, stream>>>(dstA, cursor);
    scan_kernel<<<1, 1024, 0, stream>>>(cursor, rowptr);
    scatter_kernel<<<(N_EDGES + 255) / 256, 256, 0, stream>>>(dstA, cursor, csr);

    encoder_kernel<<<2048, 256, 0, stream>>>(x, Wn, bn0, u);

    const int NB = (N_NODES + 127) / 128;  // 782
    for (int l = 0; l < L_LAYERS; l++) {
        (void)hipMemsetAsync(stats, 0, 6144 * sizeof(float), stream);
        front_kernel<<<NB, 512, 0, stream>>>(
            u, ea, srcA, rowptr, csr, We + (size_t)l * DE * D, bee + (size_t)l * D,
            eps, l, (l > 0) ? 1 : 0, aff2a, aff2b,
            W1 + (size_t)l * D * TWO_D, b1 + (size_t)l * TWO_D, t, s1, s1sq);
        finalize_kernel<<<1, 256, 0, stream>>>(s1, s1sq, TWO_D, g1 + (size_t)l * TWO_D,
                                               bt1 + (size_t)l * TWO_D, aff1a, aff1b);
        gemm2_kernel<<<NB, 256, 0, stream>>>(
            t, aff1a, aff1b, W2 + (size_t)l * TWO_D * D, b2 + (size_t)l * D, u, s2, s2sq);
        finalize_kernel<<<1, 128, 0, stream>>>(s2, s2sq, D, gamma + (size_t)l * D,
                                               beta + (size_t)l * D, aff2a, aff2b);
    }
    apply_final_kernel<<<4096, 256, 0, stream>>>(u, aff2a, aff2b, out);
}

// Round 6
// 2141.924 us; speedup vs baseline: 1.7528x; 1.1337x over previous
//
#include <hip/hip_runtime.h>
#include <hip/hip_bf16.h>

#define N_NODES 100000
#define N_EDGES 600000
#define DIN 64
#define DE 8
#define D 128
#define TWO_D 256
#define L_LAYERS 5
#define BN_EPS 1e-5f

typedef unsigned short u16;
typedef __attribute__((ext_vector_type(8))) short short8;   // 8 bf16 MFMA A/B frag
typedef __attribute__((ext_vector_type(4))) float f32x4;    // MFMA C/D frag / native float4

__device__ inline u16 f2bf(float f) {
    __hip_bfloat16 h = __float2bfloat16(f);
    return *reinterpret_cast<u16*>(&h);
}
__device__ inline float bf2f(u16 u) {
    union { unsigned int i; float f; } v;
    v.i = ((unsigned int)u) << 16;
    return v.f;
}

// ---------------- CSR build ----------------

__global__ void hist_kernel(const int* __restrict__ dst, int* __restrict__ deg) {
    int i = blockIdx.x * blockDim.x + threadIdx.x;
    if (i < N_EDGES) atomicAdd(&deg[dst[i]], 1);
}

// in-place: cur[] holds degrees on entry, running-prefix (cursor) on exit
__global__ void scan_kernel(int* __restrict__ cur, int* __restrict__ rowptr) {
    __shared__ int part[1024];
    const int CH = (N_NODES + 1023) / 1024;
    int t = threadIdx.x;
    int s = t * CH;
    int e = s + CH; if (e > N_NODES) e = N_NODES;
    int sum = 0;
    for (int i = s; i < e; i++) sum += cur[i];
    part[t] = sum;
    __syncthreads();
    for (int off = 1; off < 1024; off <<= 1) {
        int v = (t >= off) ? part[t - off] : 0;
        __syncthreads();
        part[t] += v;
        __syncthreads();
    }
    int run = part[t] - sum;  // exclusive prefix
    for (int i = s; i < e; i++) {
        int d = cur[i];
        rowptr[i] = run;
        cur[i] = run;
        run += d;
    }
    if (t == 1023) rowptr[N_NODES] = part[1023];
}

__global__ void scatter_kernel(const int* __restrict__ dst, int* __restrict__ cursor,
                               int* __restrict__ csr) {
    int i = blockIdx.x * blockDim.x + threadIdx.x;
    if (i < N_EDGES) {
        int d = dst[i];
        int p = atomicAdd(&cursor[d], 1);
        csr[p] = i;
    }
}

// ---------------- node encoder: u = x @ Wn + bn0 (fp32) ----------------

__global__ void encoder_kernel(const float* __restrict__ x, const float* __restrict__ Wn,
                               const float* __restrict__ bn0, float* __restrict__ u) {
    __shared__ float WnL[DIN * D];
    __shared__ float bnL[D];
    int tid = threadIdx.x;
    for (int idx = tid; idx < DIN * D; idx += 256) WnL[idx] = Wn[idx];
    if (tid < D) bnL[tid] = bn0[tid];
    __syncthreads();
    int j = tid & 127, half = tid >> 7;
    for (int i = blockIdx.x * 2 + half; i < N_NODES; i += gridDim.x * 2) {
        const float* xr = x + (size_t)i * DIN;
        float acc = bnL[j];
#pragma unroll
        for (int k = 0; k < DIN; k++) acc = fmaf(xr[k], WnL[k * D + j], acc);
        u[(size_t)i * D + j] = acc;
    }
}

// ---------------- front: fused [BN2-apply ∘ gather ∘ GEMM1] ----------------
// LDS union: W1-tile (Bs) is read into per-wave registers, then the SAME LDS
// is reused for Ah/Al by the gather. 75.5 KB -> 2 blocks/CU (16 waves/CU).

__launch_bounds__(512, 4)
__global__ void front_kernel(const float* __restrict__ u, const float* __restrict__ ea,
                             const int* __restrict__ src, const int* __restrict__ rowptr,
                             const int* __restrict__ csr, const float* __restrict__ We,
                             const float* __restrict__ bee, const float* __restrict__ epsArr,
                             int layer, int use_aff, const float* __restrict__ aff2a,
                             const float* __restrict__ aff2b, const float* __restrict__ W1,
                             const float* __restrict__ b1, float* __restrict__ t,
                             float* __restrict__ s1, float* __restrict__ s1sq) {
    __shared__ u16 UNI[2 * 128 * 136];   // union: {Ws 256x136} then {Ah,Al 128x136 each}
    __shared__ float WeL[DE * D];
    __shared__ float beeL[D];
    __shared__ float affA[D];
    __shared__ float affB[D];
    __shared__ float sred[512];

    u16* Ws = UNI;
    u16* Ah = UNI;
    u16* Al = UNI + 128 * 136;

    int tid = threadIdx.x;
    int row0 = blockIdx.x * 128;

    for (int i = tid; i < DE * D; i += 512) WeL[i] = We[i];
    if (tid < D) {
        beeL[tid] = bee[tid];
        affA[tid] = aff2a[tid];
        affB[tid] = aff2b[tid];
    }
    sred[tid] = 0.f;

    // ---- phase 0: stage W1 fp32 [128][256] -> Ws[n][k] bf16, transposed ----
    {
#pragma unroll
        for (int p = 0; p < 16; p++) {
            int idx = tid + p * 512;
            int k = idx >> 6, n4 = (idx & 63) * 4;
            float4 w = *(const float4*)(W1 + (size_t)k * TWO_D + n4);
            Ws[(n4 + 0) * 136 + k] = f2bf(w.x);
            Ws[(n4 + 1) * 136 + k] = f2bf(w.y);
            Ws[(n4 + 2) * 136 + k] = f2bf(w.z);
            Ws[(n4 + 3) * 136 + k] = f2bf(w.w);
        }
    }
    __syncthreads();

    // ---- phase 1: each wave pulls its 16 B fragments into registers ----
    int lane = tid & 63, wave = tid >> 6;
    int wr = wave >> 2, wc = wave & 3;      // 2 row-groups x 4 col-groups
    int m16 = lane & 15, kq = lane >> 4;
    short8 Bf[4][4];                        // [ks][ct] : 64 VGPRs
#pragma unroll
    for (int ks = 0; ks < 4; ks++)
#pragma unroll
        for (int ct = 0; ct < 4; ct++)
            Bf[ks][ct] = *(const short8*)(&Ws[(wc * 64 + ct * 16 + m16) * 136 + ks * 32 + kq * 8]);
    __syncthreads();   // all B reads done before gather overwrites UNI

    // ---- phase 2: gather -> Ah/Al (4-edge chunks, deep load pipeline) ----
    float epsv = 1.0f + epsArr[layer];
    int j = tid & 63, sub = tid >> 6;
    for (int r = sub; r < 128; r += 8) {
        int n = row0 + r;
        float za = 0.f, zb = 0.f;
        if (n < N_NODES) {
            int p0 = rowptr[n], p1 = rowptr[n + 1];
            int cnt = p1 - p0;
            float acc_a = 0.f, acc_b = 0.f;
            int e[4], s[4];
#pragma unroll
            for (int i = 0; i < 4; i++) e[i] = (p0 + i < p1) ? csr[p0 + i] : 0;
#pragma unroll
            for (int i = 0; i < 4; i++) s[i] = src[e[i]];
            for (int base = 0; base < cnt; base += 4) {
                int m = cnt - base;  // valid edges this chunk
                float va[4], vb[4];
                float4 e0[4], e1[4];
#pragma unroll
                for (int i = 0; i < 4; i++) {
                    int ss = s[i];
                    va[i] = u[(size_t)ss * D + j];
                    vb[i] = u[(size_t)ss * D + 64 + j];
                    e0[i] = *(const float4*)(ea + (size_t)e[i] * DE);
                    e1[i] = *(const float4*)(ea + (size_t)e[i] * DE + 4);
                }
                int e2[4], s2[4];
#pragma unroll
                for (int i = 0; i < 4; i++) {
                    int p = p0 + base + 4 + i;
                    e2[i] = (p < p1) ? csr[p] : 0;
                }
#pragma unroll
                for (int i = 0; i < 4; i++) s2[i] = src[e2[i]];
#pragma unroll
                for (int i = 0; i < 4; i++) {
                    float ha = va[i], hb = vb[i];
                    if (use_aff) {
                        ha = fmaxf(fmaf(affA[j], ha, affB[j]), 0.f);
                        hb = fmaxf(fmaf(affA[64 + j], hb, affB[64 + j]), 0.f);
                    }
                    float eeA = beeL[j], eeB = beeL[64 + j];
                    eeA = fmaf(e0[i].x, WeL[0 * D + j], eeA);
                    eeB = fmaf(e0[i].x, WeL[0 * D + 64 + j], eeB);
                    eeA = fmaf(e0[i].y, WeL[1 * D + j], eeA);
                    eeB = fmaf(e0[i].y, WeL[1 * D + 64 + j], eeB);
                    eeA = fmaf(e0[i].z, WeL[2 * D + j], eeA);
                    eeB = fmaf(e0[i].z, WeL[2 * D + 64 + j], eeB);
                    eeA = fmaf(e0[i].w, WeL[3 * D + j], eeA);
                    eeB = fmaf(e0[i].w, WeL[3 * D + 64 + j], eeB);
                    eeA = fmaf(e1[i].x, WeL[4 * D + j], eeA);
                    eeB = fmaf(e1[i].x, WeL[4 * D + 64 + j], eeB);
                    eeA = fmaf(e1[i].y, WeL[5 * D + j], eeA);
                    eeB = fmaf(e1[i].y, WeL[5 * D + 64 + j], eeB);
                    eeA = fmaf(e1[i].z, WeL[6 * D + j], eeA);
                    eeB = fmaf(e1[i].z, WeL[6 * D + 64 + j], eeB);
                    eeA = fmaf(e1[i].w, WeL[7 * D + j], eeA);
                    eeB = fmaf(e1[i].w, WeL[7 * D + 64 + j], eeB);
                    float ma = fmaxf(ha + eeA, 0.f);
                    float mb = fmaxf(hb + eeB, 0.f);
                    acc_a += (i < m) ? ma : 0.f;
                    acc_b += (i < m) ? mb : 0.f;
                }
#pragma unroll
                for (int i = 0; i < 4; i++) { e[i] = e2[i]; s[i] = s2[i]; }
            }
            float oa = u[(size_t)n * D + j], ob = u[(size_t)n * D + 64 + j];
            if (use_aff) {
                oa = fmaxf(fmaf(affA[j], oa, affB[j]), 0.f);
                ob = fmaxf(fmaf(affA[64 + j], ob, affB[64 + j]), 0.f);
            }
            za = fmaf(epsv, oa, acc_a);
            zb = fmaf(epsv, ob, acc_b);
        }
        u16 hi_a = f2bf(za);
        u16 hi_b = f2bf(zb);
        Ah[r * 136 + j] = hi_a;
        Ah[r * 136 + 64 + j] = hi_b;
        Al[r * 136 + j] = f2bf(za - bf2f(hi_a));
        Al[r * 136 + 64 + j] = f2bf(zb - bf2f(hi_b));
    }
    __syncthreads();

    // ---- phase 3: MFMA, B from registers ----
    f32x4 acc[4][4];
#pragma unroll
    for (int i = 0; i < 4; i++)
#pragma unroll
        for (int c = 0; c < 4; c++) acc[i][c] = (f32x4){0.f, 0.f, 0.f, 0.f};
#pragma unroll
    for (int ks = 0; ks < 4; ks++) {
        int k0 = ks * 32 + kq * 8;
        short8 ah[4], al[4];
#pragma unroll
        for (int rt = 0; rt < 4; rt++) {
            ah[rt] = *(const short8*)(&Ah[(wr * 64 + rt * 16 + m16) * 136 + k0]);
            al[rt] = *(const short8*)(&Al[(wr * 64 + rt * 16 + m16) * 136 + k0]);
        }
#pragma unroll
        for (int rt = 0; rt < 4; rt++)
#pragma unroll
            for (int ct = 0; ct < 4; ct++) {
                acc[rt][ct] = __builtin_amdgcn_mfma_f32_16x16x32_bf16(ah[rt], Bf[ks][ct],
                                                                     acc[rt][ct], 0, 0, 0);
                acc[rt][ct] = __builtin_amdgcn_mfma_f32_16x16x32_bf16(al[rt], Bf[ks][ct],
                                                                     acc[rt][ct], 0, 0, 0);
            }
    }

    // ---- epilogue: bias, non-temporal fp32 store to t, BN1 stats ----
#pragma unroll
    for (int ct = 0; ct < 4; ct++) {
        int col = wc * 64 + ct * 16 + m16;
        float bias = b1[col];
        float ls = 0.f, lq = 0.f;
#pragma unroll
        for (int rt = 0; rt < 4; rt++) {
#pragma unroll
            for (int rr = 0; rr < 4; rr++) {
                int row = row0 + wr * 64 + rt * 16 + kq * 4 + rr;
                if (row < N_NODES) {
                    float v = acc[rt][ct][rr] + bias;
                    __builtin_nontemporal_store(v, &t[(size_t)row * TWO_D + col]);
                    ls += v;
                    lq += v * v;
                }
            }
        }
        atomicAdd(&sred[col], ls);
        atomicAdd(&sred[256 + col], lq);
    }
    __syncthreads();
    int slot = blockIdx.x & 7;
    if (tid < 256) atomicAdd(&s1[slot * TWO_D + tid], sred[tid]);
    else atomicAdd(&s1sq[slot * TWO_D + (tid - 256)], sred[tid]);
}

// ---------------- GEMM2: u = relu(aff1(t)) @ W2 + b2 (split-bf16 MFMA), BN2 stats ----
// Per-K-chunk LDS union {B-stage -> B-frags-to-reg -> A-stage} : ~39 KB -> 4 blocks/CU.

__launch_bounds__(256, 4)
__global__ void gemm2_kernel(const float* __restrict__ t, const float* __restrict__ aff1a,
                             const float* __restrict__ aff1b, const float* __restrict__ W2,
                             const float* __restrict__ b2, float* __restrict__ u,
                             float* __restrict__ s2, float* __restrict__ s2sq) {
    __shared__ u16 CH[2 * 128 * 72];   // union: {Bs 128x72} / {Ah,Al 128x72 each}
    __shared__ float affL[512];
    __shared__ float sred[256];
    u16* BsC = CH;
    u16* AhC = CH;
    u16* AlC = CH + 128 * 72;

    int tid = threadIdx.x;
    int row0 = blockIdx.x * 128;
    affL[tid] = aff1a[tid];
    affL[256 + tid] = aff1b[tid];
    sred[tid] = 0.f;

    int lane = tid & 63, wave = tid >> 6;
    int wr = wave >> 1, wc = wave & 1;
    int m16 = lane & 15, kq = lane >> 4;
    f32x4 acc[4][4];
#pragma unroll
    for (int i = 0; i < 4; i++)
#pragma unroll
        for (int c = 0; c < 4; c++) acc[i][c] = (f32x4){0.f, 0.f, 0.f, 0.f};
    __syncthreads();

    for (int kc = 0; kc < 4; kc++) {
        // B staging: W2 fp32 [256][128] chunk -> BsC[n][k] bf16 transposed
#pragma unroll
        for (int p = 0; p < 8; p++) {
            int idx = tid + p * 256;
            int kk = idx >> 5, n4 = (idx & 31) * 4;
            float4 w = *(const float4*)(W2 + (size_t)(kc * 64 + kk) * D + n4);
            BsC[(n4 + 0) * 72 + kk] = f2bf(w.x);
            BsC[(n4 + 1) * 72 + kk] = f2bf(w.y);
            BsC[(n4 + 2) * 72 + kk] = f2bf(w.z);
            BsC[(n4 + 3) * 72 + kk] = f2bf(w.w);
        }
        __syncthreads();
        short8 Bf[2][4];   // [ks][ct] for this chunk
#pragma unroll
        for (int ks = 0; ks < 2; ks++)
#pragma unroll
            for (int ct = 0; ct < 4; ct++)
                Bf[ks][ct] = *(const short8*)(&BsC[(wc * 64 + ct * 16 + m16) * 72 + ks * 32 + kq * 8]);
        __syncthreads();   // B reads done before A overwrites

        // A staging: t fp32 -> relu(aff1) -> hi/lo bf16
#pragma unroll
        for (int p = 0; p < 8; p++) {
            int idx = tid + p * 256;
            int row = idx >> 4, c4 = (idx & 15) * 4;
            f32x4 v = (f32x4){0.f, 0.f, 0.f, 0.f};
            if (row0 + row < N_NODES)
                v = *(const f32x4*)(t + (size_t)(row0 + row) * TWO_D + kc * 64 + c4);
            u16 hi4[4], lo4[4];
#pragma unroll
            for (int i = 0; i < 4; i++) {
                int k = kc * 64 + c4 + i;
                float g = fmaxf(fmaf(affL[k], v[i], affL[256 + k]), 0.f);
                u16 hi = f2bf(g);
                hi4[i] = hi;
                lo4[i] = f2bf(g - bf2f(hi));
            }
            *(uint2*)(&AhC[row * 72 + c4]) = *(const uint2*)hi4;
            *(uint2*)(&AlC[row * 72 + c4]) = *(const uint2*)lo4;
        }
        __syncthreads();
#pragma unroll
        for (int ks = 0; ks < 2; ks++) {
            int k0 = ks * 32 + kq * 8;
            short8 ah[4], al[4];
#pragma unroll
            for (int rt = 0; rt < 4; rt++) {
                ah[rt] = *(const short8*)(&AhC[(wr * 64 + rt * 16 + m16) * 72 + k0]);
                al[rt] = *(const short8*)(&AlC[(wr * 64 + rt * 16 + m16) * 72 + k0]);
            }
#pragma unroll
            for (int rt = 0; rt < 4; rt++)
#pragma unroll
                for (int ct = 0; ct < 4; ct++) {
                    acc[rt][ct] = __builtin_amdgcn_mfma_f32_16x16x32_bf16(ah[rt], Bf[ks][ct],
                                                                         acc[rt][ct], 0, 0, 0);
                    acc[rt][ct] = __builtin_amdgcn_mfma_f32_16x16x32_bf16(al[rt], Bf[ks][ct],
                                                                         acc[rt][ct], 0, 0, 0);
                }
        }
        __syncthreads();   // A reads done before next chunk's B stage
    }

    // epilogue: bias, fp32 store to u, BN2 stats
#pragma unroll
    for (int ct = 0; ct < 4; ct++) {
        int col = wc * 64 + ct * 16 + m16;
        float bias = b2[col];
        float ls = 0.f, lq = 0.f;
#pragma unroll
        for (int rt = 0; rt < 4; rt++) {
#pragma unroll
            for (int rr = 0; rr < 4; rr++) {
                int row = row0 + wr * 64 + rt * 16 + kq * 4 + rr;
                if (row < N_NODES) {
                    float v = acc[rt][ct][rr] + bias;
                    u[(size_t)row * D + col] = v;
                    ls += v;
                    lq += v * v;
                }
            }
        }
        atomicAdd(&sred[col], ls);
        atomicAdd(&sred[128 + col], lq);
    }
    __syncthreads();
    int slot = blockIdx.x & 7;
    if (tid < 128) atomicAdd(&s2[slot * D + tid], sred[tid]);
    else atomicAdd(&s2sq[slot * D + (tid - 128)], sred[tid]);
}

// ---------------- BN finalize ----------------

__global__ void finalize_kernel(const float* __restrict__ sums, const float* __restrict__ sumsq,
                                int ncols, const float* __restrict__ g,
                                const float* __restrict__ bt, float* __restrict__ affa,
                                float* __restrict__ affb) {
    int j = threadIdx.x;
    if (j < ncols) {
        float s = 0.f, q = 0.f;
        for (int k = 0; k < 8; k++) { s += sums[k * ncols + j]; q += sumsq[k * ncols + j]; }
        const float invN = 1.0f / (float)N_NODES;
        float mean = s * invN;
        float var = q * invN - mean * mean;
        float rstd = rsqrtf(var + BN_EPS);
        float a = g[j] * rstd;
        affa[j] = a;
        affb[j] = fmaf(-a, mean, bt[j]);
    }
}

// ---------------- final BN2 apply (no relu) -> out ----------------

__global__ void apply_final_kernel(const float* __restrict__ u, const float* __restrict__ a,
                                   const float* __restrict__ b, float* __restrict__ out) {
    const int total = N_NODES * D / 4;
    for (int idx = blockIdx.x * blockDim.x + threadIdx.x; idx < total;
         idx += gridDim.x * blockDim.x) {
        int j4 = (idx & 31) * 4;
        float4 uv = ((const float4*)u)[idx];
        float4 av = *(const float4*)(a + j4);
        float4 bv = *(const float4*)(b + j4);
        float4 o;
        o.x = fmaf(av.x, uv.x, bv.x);
        o.y = fmaf(av.y, uv.y, bv.y);
        o.z = fmaf(av.z, uv.z, bv.z);
        o.w = fmaf(av.w, uv.w, bv.w);
        ((float4*)out)[idx] = o;
    }
}

// ---------------- launch ----------------

extern "C" void kernel_launch(void* const* d_in, const int* in_sizes, int n_in,
                              void* d_out, int out_size, void* d_ws, size_t ws_size,
                              hipStream_t stream) {
    (void)in_sizes; (void)n_in; (void)out_size; (void)ws_size;
    const float* x    = (const float*)d_in[0];
    const int*   ei   = (const int*)d_in[1];
    const float* ea   = (const float*)d_in[2];
    const float* Wn   = (const float*)d_in[3];
    const float* bn0  = (const float*)d_in[4];
    const float* We   = (const float*)d_in[5];
    const float* bee  = (const float*)d_in[6];
    const float* W1   = (const float*)d_in[7];
    const float* b1   = (const float*)d_in[8];
    const float* g1   = (const float*)d_in[9];
    const float* bt1  = (const float*)d_in[10];
    const float* W2   = (const float*)d_in[11];
    const float* b2   = (const float*)d_in[12];
    const float* eps  = (const float*)d_in[13];
    const float* gamma= (const float*)d_in[14];
    const float* beta = (const float*)d_in[15];
    float* out = (float*)d_out;

    // workspace layout (total ~157 MB)
    float* u      = (float*)d_ws;                      // N*128 fp32
    float* t      = u + (size_t)N_NODES * D;           // N*256 fp32
    int*   rowptr = (int*)(t + (size_t)N_NODES * TWO_D);  // N+1
    int*   cursor = rowptr + (N_NODES + 1);            // N (deg then cursor, in place)
    int*   csr    = cursor + N_NODES;                  // E
    float* stats  = (float*)(csr + N_EDGES);
    float* s1    = stats;            // [8][256]
    float* s1sq  = stats + 2048;     // [8][256]
    float* s2    = stats + 4096;     // [8][128]
    float* s2sq  = stats + 5120;     // [8][128]
    float* aff1a = stats + 6144;     // [256]
    float* aff1b = stats + 6400;     // [256]
    float* aff2a = stats + 6656;     // [128]
    float* aff2b = stats + 6784;     // [128]

    const int* srcA = ei;
    const int* dstA = ei + N_EDGES;

    (void)hipMemsetAsync(cursor, 0, N_NODES * sizeof(int), stream);
    hist_kernel<<<(N_EDGES + 255) / 256, 256, 0, stream>>>(dstA, cursor);
    scan_kernel<<<1, 1024, 0, stream>>>(cursor, rowptr);
    scatter_kernel<<<(N_EDGES + 255) / 256, 256, 0, stream>>>(dstA, cursor, csr);

    encoder_kernel<<<2048, 256, 0, stream>>>(x, Wn, bn0, u);

    const int NB = (N_NODES + 127) / 128;  // 782
    for (int l = 0; l < L_LAYERS; l++) {
        (void)hipMemsetAsync(stats, 0, 6144 * sizeof(float), stream);
        front_kernel<<<NB, 512, 0, stream>>>(
            u, ea, srcA, rowptr, csr, We + (size_t)l * DE * D, bee + (size_t)l * D,
            eps, l, (l > 0) ? 1 : 0, aff2a, aff2b,
            W1 + (size_t)l * D * TWO_D, b1 + (size_t)l * TWO_D, t, s1, s1sq);
        finalize_kernel<<<1, 256, 0, stream>>>(s1, s1sq, TWO_D, g1 + (size_t)l * TWO_D,
                                               bt1 + (size_t)l * TWO_D, aff1a, aff1b);
        gemm2_kernel<<<NB, 256, 0, stream>>>(
            t, aff1a, aff1b, W2 + (size_t)l * TWO_D * D, b2 + (size_t)l * D, u, s2, s2sq);
        finalize_kernel<<<1, 128, 0, stream>>>(s2, s2sq, D, gamma + (size_t)l * D,
                                               beta + (size_t)l * D, aff2a, aff2b);
    }
    apply_final_kernel<<<4096, 256, 0, stream>>>(u, aff2a, aff2b, out);
}

// Round 7
// 1929.741 us; speedup vs baseline: 1.9456x; 1.1100x over previous
//
#include <hip/hip_runtime.h>
#include <hip/hip_bf16.h>

#define N_NODES 100000
#define N_EDGES 600000
#define DIN 64
#define DE 8
#define D 128
#define TWO_D 256
#define L_LAYERS 5
#define BN_EPS 1e-5f

#define SCAN_B 256
#define SCAN_NB ((N_NODES + SCAN_B - 1) / SCAN_B)   // 391

typedef unsigned short u16;
typedef __attribute__((ext_vector_type(8))) short short8;   // 8 bf16 MFMA A/B frag
typedef __attribute__((ext_vector_type(4))) float f32x4;    // MFMA C/D frag / native float4

__device__ inline u16 f2bf(float f) {
    __hip_bfloat16 h = __float2bfloat16(f);
    return *reinterpret_cast<u16*>(&h);
}
__device__ inline float bf2f(u16 u) {
    union { unsigned int i; float f; } v;
    v.i = ((unsigned int)u) << 16;
    return v.f;
}

// ---------------- CSR build ----------------

__global__ void hist_kernel(const int* __restrict__ dst, int* __restrict__ deg) {
    int i = blockIdx.x * blockDim.x + threadIdx.x;
    if (i < N_EDGES) atomicAdd(&deg[dst[i]], 1);
}

// phase A: per-block chunk sums
__global__ void scan_partial_kernel(const int* __restrict__ deg, int* __restrict__ blocksum) {
    __shared__ int red[SCAN_B];
    int tid = threadIdx.x;
    int i = blockIdx.x * SCAN_B + tid;
    red[tid] = (i < N_NODES) ? deg[i] : 0;
    __syncthreads();
    for (int off = SCAN_B / 2; off > 0; off >>= 1) {
        if (tid < off) red[tid] += red[tid + off];
        __syncthreads();
    }
    if (tid == 0) blocksum[blockIdx.x] = red[0];
}

// phase B: single block exclusive-scans the block sums (SCAN_NB <= 512)
__global__ void scan_blocks_kernel(int* __restrict__ blocksum, int* __restrict__ total) {
    __shared__ int sh[512];
    int tid = threadIdx.x;
    int v = (tid < SCAN_NB) ? blocksum[tid] : 0;
    sh[tid] = v;
    __syncthreads();
    for (int off = 1; off < 512; off <<= 1) {
        int w = (tid >= off) ? sh[tid - off] : 0;
        __syncthreads();
        sh[tid] += w;
        __syncthreads();
    }
    if (tid < SCAN_NB) blocksum[tid] = sh[tid] - v;  // exclusive
    if (tid == 511) *total = sh[511];
}

// phase C: intra-block exclusive scan + block offset -> rowptr & cursor
__global__ void scan_apply_kernel(const int* __restrict__ deg, const int* __restrict__ blocksum,
                                  const int* __restrict__ total, int* __restrict__ rowptr,
                                  int* __restrict__ cursor) {
    __shared__ int sh[SCAN_B];
    int tid = threadIdx.x;
    int i = blockIdx.x * SCAN_B + tid;
    int v = (i < N_NODES) ? deg[i] : 0;
    sh[tid] = v;
    __syncthreads();
    for (int off = 1; off < SCAN_B; off <<= 1) {
        int w = (tid >= off) ? sh[tid - off] : 0;
        __syncthreads();
        sh[tid] += w;
        __syncthreads();
    }
    if (i < N_NODES) {
        int p = blocksum[blockIdx.x] + sh[tid] - v;  // exclusive prefix
        rowptr[i] = p;
        cursor[i] = p;
    }
    if (i == N_NODES - 1) rowptr[N_NODES] = *total;
}

__global__ void scatter_kernel(const int* __restrict__ dst, int* __restrict__ cursor,
                               int* __restrict__ csr) {
    int i = blockIdx.x * blockDim.x + threadIdx.x;
    if (i < N_EDGES) {
        int d = dst[i];
        int p = atomicAdd(&cursor[d], 1);
        csr[p] = i;
    }
}

// ---------------- node encoder: u = x @ Wn + bn0 (fp32) ----------------

__global__ void encoder_kernel(const float* __restrict__ x, const float* __restrict__ Wn,
                               const float* __restrict__ bn0, float* __restrict__ u) {
    __shared__ float WnL[DIN * D];
    __shared__ float bnL[D];
    int tid = threadIdx.x;
    for (int idx = tid; idx < DIN * D; idx += 256) WnL[idx] = Wn[idx];
    if (tid < D) bnL[tid] = bn0[tid];
    __syncthreads();
    int j = tid & 127, half = tid >> 7;
    for (int i = blockIdx.x * 2 + half; i < N_NODES; i += gridDim.x * 2) {
        const float* xr = x + (size_t)i * DIN;
        float acc = bnL[j];
#pragma unroll
        for (int k = 0; k < DIN; k++) acc = fmaf(xr[k], WnL[k * D + j], acc);
        u[(size_t)i * D + j] = acc;
    }
}

// ---------------- front: fused [BN2-apply ∘ gather ∘ GEMM1] ----------------
// LDS union: W1-tile (Bs) is read into per-wave registers, then the SAME LDS
// is reused for Ah/Al by the gather. 75.5 KB -> 2 blocks/CU (16 waves/CU).

__launch_bounds__(512, 4)
__global__ void front_kernel(const float* __restrict__ u, const float* __restrict__ ea,
                             const int* __restrict__ src, const int* __restrict__ rowptr,
                             const int* __restrict__ csr, const float* __restrict__ We,
                             const float* __restrict__ bee, const float* __restrict__ epsArr,
                             int layer, int use_aff, const float* __restrict__ aff2a,
                             const float* __restrict__ aff2b, const float* __restrict__ W1,
                             const float* __restrict__ b1, float* __restrict__ t,
                             float* __restrict__ s1, float* __restrict__ s1sq) {
    __shared__ u16 UNI[2 * 128 * 136];   // union: {Ws 256x136} then {Ah,Al 128x136 each}
    __shared__ float WeL[DE * D];
    __shared__ float beeL[D];
    __shared__ float affA[D];
    __shared__ float affB[D];
    __shared__ float sred[512];

    u16* Ws = UNI;
    u16* Ah = UNI;
    u16* Al = UNI + 128 * 136;

    int tid = threadIdx.x;
    int row0 = blockIdx.x * 128;

    for (int i = tid; i < DE * D; i += 512) WeL[i] = We[i];
    if (tid < D) {
        beeL[tid] = bee[tid];
        affA[tid] = aff2a[tid];
        affB[tid] = aff2b[tid];
    }
    sred[tid] = 0.f;

    // ---- phase 0: stage W1 fp32 [128][256] -> Ws[n][k] bf16, transposed ----
    {
#pragma unroll
        for (int p = 0; p < 16; p++) {
            int idx = tid + p * 512;
            int k = idx >> 6, n4 = (idx & 63) * 4;
            float4 w = *(const float4*)(W1 + (size_t)k * TWO_D + n4);
            Ws[(n4 + 0) * 136 + k] = f2bf(w.x);
            Ws[(n4 + 1) * 136 + k] = f2bf(w.y);
            Ws[(n4 + 2) * 136 + k] = f2bf(w.z);
            Ws[(n4 + 3) * 136 + k] = f2bf(w.w);
        }
    }
    __syncthreads();

    // ---- phase 1: each wave pulls its 16 B fragments into registers ----
    int lane = tid & 63, wave = tid >> 6;
    int wr = wave >> 2, wc = wave & 3;      // 2 row-groups x 4 col-groups
    int m16 = lane & 15, kq = lane >> 4;
    short8 Bf[4][4];                        // [ks][ct] : 64 VGPRs
#pragma unroll
    for (int ks = 0; ks < 4; ks++)
#pragma unroll
        for (int ct = 0; ct < 4; ct++)
            Bf[ks][ct] = *(const short8*)(&Ws[(wc * 64 + ct * 16 + m16) * 136 + ks * 32 + kq * 8]);
    __syncthreads();   // all B reads done before gather overwrites UNI

    // ---- phase 2: gather -> Ah/Al (4-edge chunks, deep load pipeline) ----
    float epsv = 1.0f + epsArr[layer];
    int j = tid & 63, sub = tid >> 6;
    for (int r = sub; r < 128; r += 8) {
        int n = row0 + r;
        float za = 0.f, zb = 0.f;
        if (n < N_NODES) {
            int p0 = rowptr[n], p1 = rowptr[n + 1];
            int cnt = p1 - p0;
            float acc_a = 0.f, acc_b = 0.f;
            int e[4], s[4];
#pragma unroll
            for (int i = 0; i < 4; i++) e[i] = (p0 + i < p1) ? csr[p0 + i] : 0;
#pragma unroll
            for (int i = 0; i < 4; i++) s[i] = src[e[i]];
            for (int base = 0; base < cnt; base += 4) {
                int m = cnt - base;  // valid edges this chunk
                float va[4], vb[4];
                float4 e0[4], e1[4];
#pragma unroll
                for (int i = 0; i < 4; i++) {
                    int ss = s[i];
                    va[i] = u[(size_t)ss * D + j];
                    vb[i] = u[(size_t)ss * D + 64 + j];
                    e0[i] = *(const float4*)(ea + (size_t)e[i] * DE);
                    e1[i] = *(const float4*)(ea + (size_t)e[i] * DE + 4);
                }
                int e2[4], s2[4];
#pragma unroll
                for (int i = 0; i < 4; i++) {
                    int p = p0 + base + 4 + i;
                    e2[i] = (p < p1) ? csr[p] : 0;
                }
#pragma unroll
                for (int i = 0; i < 4; i++) s2[i] = src[e2[i]];
#pragma unroll
                for (int i = 0; i < 4; i++) {
                    float ha = va[i], hb = vb[i];
                    if (use_aff) {
                        ha = fmaxf(fmaf(affA[j], ha, affB[j]), 0.f);
                        hb = fmaxf(fmaf(affA[64 + j], hb, affB[64 + j]), 0.f);
                    }
                    float eeA = beeL[j], eeB = beeL[64 + j];
                    eeA = fmaf(e0[i].x, WeL[0 * D + j], eeA);
                    eeB = fmaf(e0[i].x, WeL[0 * D + 64 + j], eeB);
                    eeA = fmaf(e0[i].y, WeL[1 * D + j], eeA);
                    eeB = fmaf(e0[i].y, WeL[1 * D + 64 + j], eeB);
                    eeA = fmaf(e0[i].z, WeL[2 * D + j], eeA);
                    eeB = fmaf(e0[i].z, WeL[2 * D + 64 + j], eeB);
                    eeA = fmaf(e0[i].w, WeL[3 * D + j], eeA);
                    eeB = fmaf(e0[i].w, WeL[3 * D + 64 + j], eeB);
                    eeA = fmaf(e1[i].x, WeL[4 * D + j], eeA);
                    eeB = fmaf(e1[i].x, WeL[4 * D + 64 + j], eeB);
                    eeA = fmaf(e1[i].y, WeL[5 * D + j], eeA);
                    eeB = fmaf(e1[i].y, WeL[5 * D + 64 + j], eeB);
                    eeA = fmaf(e1[i].z, WeL[6 * D + j], eeA);
                    eeB = fmaf(e1[i].z, WeL[6 * D + 64 + j], eeB);
                    eeA = fmaf(e1[i].w, WeL[7 * D + j], eeA);
                    eeB = fmaf(e1[i].w, WeL[7 * D + 64 + j], eeB);
                    float ma = fmaxf(ha + eeA, 0.f);
                    float mb = fmaxf(hb + eeB, 0.f);
                    acc_a += (i < m) ? ma : 0.f;
                    acc_b += (i < m) ? mb : 0.f;
                }
#pragma unroll
                for (int i = 0; i < 4; i++) { e[i] = e2[i]; s[i] = s2[i]; }
            }
            float oa = u[(size_t)n * D + j], ob = u[(size_t)n * D + 64 + j];
            if (use_aff) {
                oa = fmaxf(fmaf(affA[j], oa, affB[j]), 0.f);
                ob = fmaxf(fmaf(affA[64 + j], ob, affB[64 + j]), 0.f);
            }
            za = fmaf(epsv, oa, acc_a);
            zb = fmaf(epsv, ob, acc_b);
        }
        u16 hi_a = f2bf(za);
        u16 hi_b = f2bf(zb);
        Ah[r * 136 + j] = hi_a;
        Ah[r * 136 + 64 + j] = hi_b;
        Al[r * 136 + j] = f2bf(za - bf2f(hi_a));
        Al[r * 136 + 64 + j] = f2bf(zb - bf2f(hi_b));
    }
    __syncthreads();

    // ---- phase 3: MFMA, B from registers ----
    f32x4 acc[4][4];
#pragma unroll
    for (int i = 0; i < 4; i++)
#pragma unroll
        for (int c = 0; c < 4; c++) acc[i][c] = (f32x4){0.f, 0.f, 0.f, 0.f};
#pragma unroll
    for (int ks = 0; ks < 4; ks++) {
        int k0 = ks * 32 + kq * 8;
        short8 ah[4], al[4];
#pragma unroll
        for (int rt = 0; rt < 4; rt++) {
            ah[rt] = *(const short8*)(&Ah[(wr * 64 + rt * 16 + m16) * 136 + k0]);
            al[rt] = *(const short8*)(&Al[(wr * 64 + rt * 16 + m16) * 136 + k0]);
        }
#pragma unroll
        for (int rt = 0; rt < 4; rt++)
#pragma unroll
            for (int ct = 0; ct < 4; ct++) {
                acc[rt][ct] = __builtin_amdgcn_mfma_f32_16x16x32_bf16(ah[rt], Bf[ks][ct],
                                                                     acc[rt][ct], 0, 0, 0);
                acc[rt][ct] = __builtin_amdgcn_mfma_f32_16x16x32_bf16(al[rt], Bf[ks][ct],
                                                                     acc[rt][ct], 0, 0, 0);
            }
    }

    // ---- epilogue: bias, non-temporal fp32 store to t, BN1 stats ----
#pragma unroll
    for (int ct = 0; ct < 4; ct++) {
        int col = wc * 64 + ct * 16 + m16;
        float bias = b1[col];
        float ls = 0.f, lq = 0.f;
#pragma unroll
        for (int rt = 0; rt < 4; rt++) {
#pragma unroll
            for (int rr = 0; rr < 4; rr++) {
                int row = row0 + wr * 64 + rt * 16 + kq * 4 + rr;
                if (row < N_NODES) {
                    float v = acc[rt][ct][rr] + bias;
                    __builtin_nontemporal_store(v, &t[(size_t)row * TWO_D + col]);
                    ls += v;
                    lq += v * v;
                }
            }
        }
        atomicAdd(&sred[col], ls);
        atomicAdd(&sred[256 + col], lq);
    }
    __syncthreads();
    int slot = blockIdx.x & 7;
    if (tid < 256) atomicAdd(&s1[slot * TWO_D + tid], sred[tid]);
    else atomicAdd(&s1sq[slot * TWO_D + (tid - 256)], sred[tid]);
}

// ---------------- GEMM2: u = relu(aff1(t)) @ W2 + b2 (split-bf16 MFMA), BN2 stats ----
// Per-K-chunk LDS union {B-stage -> B-frags-to-reg -> A-stage} : ~39 KB -> 4 blocks/CU.

__launch_bounds__(256, 4)
__global__ void gemm2_kernel(const float* __restrict__ t, const float* __restrict__ aff1a,
                             const float* __restrict__ aff1b, const float* __restrict__ W2,
                             const float* __restrict__ b2, float* __restrict__ u,
                             float* __restrict__ s2, float* __restrict__ s2sq) {
    __shared__ u16 CH[2 * 128 * 72];   // union: {Bs 128x72} / {Ah,Al 128x72 each}
    __shared__ float affL[512];
    __shared__ float sred[256];
    u16* BsC = CH;
    u16* AhC = CH;
    u16* AlC = CH + 128 * 72;

    int tid = threadIdx.x;
    int row0 = blockIdx.x * 128;
    affL[tid] = aff1a[tid];
    affL[256 + tid] = aff1b[tid];
    sred[tid] = 0.f;

    int lane = tid & 63, wave = tid >> 6;
    int wr = wave >> 1, wc = wave & 1;
    int m16 = lane & 15, kq = lane >> 4;
    f32x4 acc[4][4];
#pragma unroll
    for (int i = 0; i < 4; i++)
#pragma unroll
        for (int c = 0; c < 4; c++) acc[i][c] = (f32x4){0.f, 0.f, 0.f, 0.f};
    __syncthreads();

    for (int kc = 0; kc < 4; kc++) {
        // B staging: W2 fp32 [256][128] chunk -> BsC[n][k] bf16 transposed
#pragma unroll
        for (int p = 0; p < 8; p++) {
            int idx = tid + p * 256;
            int kk = idx >> 5, n4 = (idx & 31) * 4;
            float4 w = *(const float4*)(W2 + (size_t)(kc * 64 + kk) * D + n4);
            BsC[(n4 + 0) * 72 + kk] = f2bf(w.x);
            BsC[(n4 + 1) * 72 + kk] = f2bf(w.y);
            BsC[(n4 + 2) * 72 + kk] = f2bf(w.z);
            BsC[(n4 + 3) * 72 + kk] = f2bf(w.w);
        }
        __syncthreads();
        short8 Bf[2][4];   // [ks][ct] for this chunk
#pragma unroll
        for (int ks = 0; ks < 2; ks++)
#pragma unroll
            for (int ct = 0; ct < 4; ct++)
                Bf[ks][ct] = *(const short8*)(&BsC[(wc * 64 + ct * 16 + m16) * 72 + ks * 32 + kq * 8]);
        __syncthreads();   // B reads done before A overwrites

        // A staging: t fp32 -> relu(aff1) -> hi/lo bf16
#pragma unroll
        for (int p = 0; p < 8; p++) {
            int idx = tid + p * 256;
            int row = idx >> 4, c4 = (idx & 15) * 4;
            f32x4 v = (f32x4){0.f, 0.f, 0.f, 0.f};
            if (row0 + row < N_NODES)
                v = *(const f32x4*)(t + (size_t)(row0 + row) * TWO_D + kc * 64 + c4);
            u16 hi4[4], lo4[4];
#pragma unroll
            for (int i = 0; i < 4; i++) {
                int k = kc * 64 + c4 + i;
                float g = fmaxf(fmaf(affL[k], v[i], affL[256 + k]), 0.f);
                u16 hi = f2bf(g);
                hi4[i] = hi;
                lo4[i] = f2bf(g - bf2f(hi));
            }
            *(uint2*)(&AhC[row * 72 + c4]) = *(const uint2*)hi4;
            *(uint2*)(&AlC[row * 72 + c4]) = *(const uint2*)lo4;
        }
        __syncthreads();
#pragma unroll
        for (int ks = 0; ks < 2; ks++) {
            int k0 = ks * 32 + kq * 8;
            short8 ah[4], al[4];
#pragma unroll
            for (int rt = 0; rt < 4; rt++) {
                ah[rt] = *(const short8*)(&AhC[(wr * 64 + rt * 16 + m16) * 72 + k0]);
                al[rt] = *(const short8*)(&AlC[(wr * 64 + rt * 16 + m16) * 72 + k0]);
            }
#pragma unroll
            for (int rt = 0; rt < 4; rt++)
#pragma unroll
                for (int ct = 0; ct < 4; ct++) {
                    acc[rt][ct] = __builtin_amdgcn_mfma_f32_16x16x32_bf16(ah[rt], Bf[ks][ct],
                                                                         acc[rt][ct], 0, 0, 0);
                    acc[rt][ct] = __builtin_amdgcn_mfma_f32_16x16x32_bf16(al[rt], Bf[ks][ct],
                                                                         acc[rt][ct], 0, 0, 0);
                }
        }
        __syncthreads();   // A reads done before next chunk's B stage
    }

    // epilogue: bias, fp32 store to u, BN2 stats
#pragma unroll
    for (int ct = 0; ct < 4; ct++) {
        int col = wc * 64 + ct * 16 + m16;
        float bias = b2[col];
        float ls = 0.f, lq = 0.f;
#pragma unroll
        for (int rt = 0; rt < 4; rt++) {
#pragma unroll
            for (int rr = 0; rr < 4; rr++) {
                int row = row0 + wr * 64 + rt * 16 + kq * 4 + rr;
                if (row < N_NODES) {
                    float v = acc[rt][ct][rr] + bias;
                    u[(size_t)row * D + col] = v;
                    ls += v;
                    lq += v * v;
                }
            }
        }
        atomicAdd(&sred[col], ls);
        atomicAdd(&sred[128 + col], lq);
    }
    __syncthreads();
    int slot = blockIdx.x & 7;
    if (tid < 128) atomicAdd(&s2[slot * D + tid], sred[tid]);
    else atomicAdd(&s2sq[slot * D + (tid - 128)], sred[tid]);
}

// ---------------- BN finalize ----------------

__global__ void finalize_kernel(const float* __restrict__ sums, const float* __restrict__ sumsq,
                                int ncols, const float* __restrict__ g,
                                const float* __restrict__ bt, float* __restrict__ affa,
                                float* __restrict__ affb) {
    int j = threadIdx.x;
    if (j < ncols) {
        float s = 0.f, q = 0.f;
        for (int k = 0; k < 8; k++) { s += sums[k * ncols + j]; q += sumsq[k * ncols + j]; }
        const float invN = 1.0f / (float)N_NODES;
        float mean = s * invN;
        float var = q * invN - mean * mean;
        float rstd = rsqrtf(var + BN_EPS);
        float a = g[j] * rstd;
        affa[j] = a;
        affb[j] = fmaf(-a, mean, bt[j]);
    }
}

// ---------------- final BN2 apply (no relu) -> out ----------------

__global__ void apply_final_kernel(const float* __restrict__ u, const float* __restrict__ a,
                                   const float* __restrict__ b, float* __restrict__ out) {
    const int total = N_NODES * D / 4;
    for (int idx = blockIdx.x * blockDim.x + threadIdx.x; idx < total;
         idx += gridDim.x * blockDim.x) {
        int j4 = (idx & 31) * 4;
        float4 uv = ((const float4*)u)[idx];
        float4 av = *(const float4*)(a + j4);
        float4 bv = *(const float4*)(b + j4);
        float4 o;
        o.x = fmaf(av.x, uv.x, bv.x);
        o.y = fmaf(av.y, uv.y, bv.y);
        o.z = fmaf(av.z, uv.z, bv.z);
        o.w = fmaf(av.w, uv.w, bv.w);
        ((float4*)out)[idx] = o;
    }
}

// ---------------- launch ----------------

extern "C" void kernel_launch(void* const* d_in, const int* in_sizes, int n_in,
                              void* d_out, int out_size, void* d_ws, size_t ws_size,
                              hipStream_t stream) {
    (void)in_sizes; (void)n_in; (void)out_size; (void)ws_size;
    const float* x    = (const float*)d_in[0];
    const int*   ei   = (const int*)d_in[1];
    const float* ea   = (const float*)d_in[2];
    const float* Wn   = (const float*)d_in[3];
    const float* bn0  = (const float*)d_in[4];
    const float* We   = (const float*)d_in[5];
    const float* bee  = (const float*)d_in[6];
    const float* W1   = (const float*)d_in[7];
    const float* b1   = (const float*)d_in[8];
    const float* g1   = (const float*)d_in[9];
    const float* bt1  = (const float*)d_in[10];
    const float* W2   = (const float*)d_in[11];
    const float* b2   = (const float*)d_in[12];
    const float* eps  = (const float*)d_in[13];
    const float* gamma= (const float*)d_in[14];
    const float* beta = (const float*)d_in[15];
    float* out = (float*)d_out;

    // workspace layout (total ~157 MB)
    float* u      = (float*)d_ws;                      // N*128 fp32
    float* t      = u + (size_t)N_NODES * D;           // N*256 fp32
    int*   rowptr = (int*)(t + (size_t)N_NODES * TWO_D);  // N+1
    int*   cursor = rowptr + (N_NODES + 1);            // N
    int*   deg    = cursor + N_NODES;                  // N
    int*   csr    = deg + N_NODES;                     // E
    int*   blocksum = csr + N_EDGES;                   // SCAN_NB + 1
    float* stats  = (float*)(blocksum + SCAN_NB + 1);
    float* s1    = stats;            // [8][256]
    float* s1sq  = stats + 2048;     // [8][256]
    float* s2    = stats + 4096;     // [8][128]
    float* s2sq  = stats + 5120;     // [8][128]
    float* aff1a = stats + 6144;     // [256]
    float* aff1b = stats + 6400;     // [256]
    float* aff2a = stats + 6656;     // [128]
    float* aff2b = stats + 6784;     // [128]
    int*   totalp = blocksum + SCAN_NB;

    const int* srcA = ei;
    const int* dstA = ei + N_EDGES;

    (void)hipMemsetAsync(deg, 0, N_NODES * sizeof(int), stream);
    hist_kernel<<<(N_EDGES + 255) / 256, 256, 0, stream>>>(dstA, deg);
    scan_partial_kernel<<<SCAN_NB, SCAN_B, 0, stream>>>(deg, blocksum);
    scan_blocks_kernel<<<1, 512, 0, stream>>>(blocksum, totalp);
    scan_apply_kernel<<<SCAN_NB, SCAN_B, 0, stream>>>(deg, blocksum, totalp, rowptr, cursor);
    scatter_kernel<<<(N_EDGES + 255) / 256, 256, 0, stream>>>(dstA, cursor, csr);

    encoder_kernel<<<2048, 256, 0, stream>>>(x, Wn, bn0, u);

    const int NB = (N_NODES + 127) / 128;  // 782
    for (int l = 0; l < L_LAYERS; l++) {
        (void)hipMemsetAsync(stats, 0, 6144 * sizeof(float), stream);
        front_kernel<<<NB, 512, 0, stream>>>(
            u, ea, srcA, rowptr, csr, We + (size_t)l * DE * D, bee + (size_t)l * D,
            eps, l, (l > 0) ? 1 : 0, aff2a, aff2b,
            W1 + (size_t)l * D * TWO_D, b1 + (size_t)l * TWO_D, t, s1, s1sq);
        finalize_kernel<<<1, 256, 0, stream>>>(s1, s1sq, TWO_D, g1 + (size_t)l * TWO_D,
                                               bt1 + (size_t)l * TWO_D, aff1a, aff1b);
        gemm2_kernel<<<NB, 256, 0, stream>>>(
            t, aff1a, aff1b, W2 + (size_t)l * TWO_D * D, b2 + (size_t)l * D, u, s2, s2sq);
        finalize_kernel<<<1, 128, 0, stream>>>(s2, s2sq, D, gamma + (size_t)l * D,
                                               beta + (size_t)l * D, aff2a, aff2b);
    }
    apply_final_kernel<<<4096, 256, 0, stream>>>(u, aff2a, aff2b, out);
}